// Round 1
// baseline (751.942 us; speedup 1.0000x reference)
//
#include <hip/hip_runtime.h>
#include <math.h>

#define DD    768
#define NQ    400
#define NROWS 408          // 400 q rows + 8 m_proj rows
#define JD    6144         // J*D = 8*768
#define WSLICE 4718592     // I*D*E = 8*768*768 (stride between j slices of W)
#define EPSF  1e-8f

// ---------------- workspace layout (floats) ----------------
#define OFF_MPROJ 0                       // [8][768]
#define OFF_H     6144                    // [408][6144]
#define OFF_HM    (6144 + 408*6144)       // [64][768]  (j*8+i major)
#define OFF_MU    (OFF_HM + 64*768)       // [64]
#define OFF_MC2   (OFF_MU + 64)           // [64]

// ---------------- kernel 1: m_proj = m @ W_n ----------------
__global__ __launch_bounds__(256) void k_mproj(const float* __restrict__ m,
                                               const float* __restrict__ Wn,
                                               float* __restrict__ mproj)
{
    const int i = blockIdx.y;                       // 0..7
    const int d = blockIdx.x * 256 + threadIdx.x;   // 0..767
    float acc = 0.f;
    #pragma unroll 8
    for (int e = 0; e < DD; ++e)
        acc += m[i*DD + e] * Wn[(size_t)e*DD + d];
    mproj[i*DD + d] = acc;
}

// ---------------- kernel 2: H[x, j*768+d] = sum_e W[j,0,d,e] * X[x,e] ----------------
// X = rows 0..399 -> q, rows 400..407 -> mproj. 64x64 tile, BK=32, 256 thr, 4x4/thread.
__global__ __launch_bounds__(256) void k_gemm(const float* __restrict__ q,
                                              const float* __restrict__ mproj,
                                              const float* __restrict__ W,
                                              float* __restrict__ H)
{
    __shared__ float As[32][68];
    __shared__ float Bs[32][68];
    const int tid = threadIdx.x;
    const int tx = tid & 15;
    const int ty = tid >> 4;
    const int c0 = blockIdx.x * 64;     // global col in [0,6144)
    const int m0 = blockIdx.y * 64;     // global row
    const int j  = c0 / DD;
    const int d0 = c0 % DD;             // 64-tiles never straddle a j boundary
    const float* Bbase = W + (size_t)j * WSLICE + (size_t)d0 * DD;  // i = 0 slice
    const int lrow = tid >> 3;          // 0..31
    const int lk   = (tid & 7) << 2;    // 0,4,...,28
    float acc[4][4] = {};

    for (int k0 = 0; k0 < DD; k0 += 32) {
        #pragma unroll
        for (int h = 0; h < 2; ++h) {
            const int r  = lrow + h * 32;
            const int gr = m0 + r;
            float4 av = make_float4(0.f, 0.f, 0.f, 0.f);
            if (gr < NROWS) {
                const float* Arow = (gr < NQ) ? (q + (size_t)gr * DD)
                                              : (mproj + (size_t)(gr - NQ) * DD);
                av = *reinterpret_cast<const float4*>(Arow + k0 + lk);
            }
            As[lk+0][r] = av.x; As[lk+1][r] = av.y; As[lk+2][r] = av.z; As[lk+3][r] = av.w;
            const float4 bv = *reinterpret_cast<const float4*>(Bbase + (size_t)r * DD + k0 + lk);
            Bs[lk+0][r] = bv.x; Bs[lk+1][r] = bv.y; Bs[lk+2][r] = bv.z; Bs[lk+3][r] = bv.w;
        }
        __syncthreads();
        #pragma unroll
        for (int k = 0; k < 32; ++k) {
            const float4 a4 = *reinterpret_cast<const float4*>(&As[k][ty * 4]);
            const float4 b4 = *reinterpret_cast<const float4*>(&Bs[k][tx * 4]);
            acc[0][0] += a4.x * b4.x; acc[0][1] += a4.x * b4.y; acc[0][2] += a4.x * b4.z; acc[0][3] += a4.x * b4.w;
            acc[1][0] += a4.y * b4.x; acc[1][1] += a4.y * b4.y; acc[1][2] += a4.y * b4.z; acc[1][3] += a4.y * b4.w;
            acc[2][0] += a4.z * b4.x; acc[2][1] += a4.z * b4.y; acc[2][2] += a4.z * b4.z; acc[2][3] += a4.z * b4.w;
            acc[3][0] += a4.w * b4.x; acc[3][1] += a4.w * b4.y; acc[3][2] += a4.w * b4.z; acc[3][3] += a4.w * b4.w;
        }
        __syncthreads();
    }
    #pragma unroll
    for (int r = 0; r < 4; ++r) {
        const int gr = m0 + ty * 4 + r;
        if (gr < NROWS) {
            float4 o = make_float4(acc[r][0], acc[r][1], acc[r][2], acc[r][3]);
            *reinterpret_cast<float4*>(H + (size_t)gr * JD + c0 + tx * 4) = o;
        }
    }
}

// ---------------- kernel 3: hat_m + Pearson stats of M rows ----------------
__global__ __launch_bounds__(256) void k_prep(const float* __restrict__ H,
                                              const float* __restrict__ b,
                                              float* __restrict__ hm,
                                              float* __restrict__ muM,
                                              float* __restrict__ mc2M)
{
    const int ji = blockIdx.x;       // j*8+i
    const int j = ji >> 3, i = ji & 7;
    const int tid = threadIdx.x;
    const int lane = tid & 63, wave = tid >> 6;
    __shared__ float scr[4];
    __shared__ float smu;
    float vals[3];
    float s = 0.f;
    #pragma unroll
    for (int u = 0; u < 3; ++u) {
        const int d = u * 256 + tid;
        float x = H[(size_t)(NQ + i) * JD + j * DD + d] + b[(size_t)ji * DD + d];
        hm[(size_t)ji * DD + d] = x;
        vals[u] = x;
        s += x;
    }
    #pragma unroll
    for (int off = 32; off; off >>= 1) s += __shfl_down(s, off);
    if (lane == 0) scr[wave] = s;
    __syncthreads();
    if (tid == 0) smu = (scr[0] + scr[1] + scr[2] + scr[3]) * (1.f / 768.f);
    __syncthreads();
    const float mu = smu;
    float s2 = 0.f;
    #pragma unroll
    for (int u = 0; u < 3; ++u) { float c = vals[u] - mu; s2 += c * c; }
    __syncthreads();
    #pragma unroll
    for (int off = 32; off; off >>= 1) s2 += __shfl_down(s2, off);
    if (lane == 0) scr[wave] = s2;
    __syncthreads();
    if (tid == 0) { muM[ji] = mu; mc2M[ji] = scr[0] + scr[1] + scr[2] + scr[3]; }
}

// ---------------- kernel 4: fused routing, one block per n ----------------
__global__ __launch_bounds__(256) void k_route(const float* __restrict__ H,
                                               const float* __restrict__ hm,
                                               const float* __restrict__ muM,
                                               const float* __restrict__ mc2M,
                                               float* __restrict__ out)
{
    const int n = blockIdx.x;
    const int tid = threadIdx.x;
    const int lane = tid & 63, wave = tid >> 6;
    __shared__ float scr[80 * 4];
    __shared__ float rout[80];
    __shared__ float sMu[64], sMc2[64], sP[64], sC1[64], sC2[64], sDotM[64];

    if (tid < 64) { sMu[tid] = muM[tid]; sMc2[tid] = mc2M[tid]; }

#define WREDUCE(val, idx) { float _v = (val);                        \
    _v += __shfl_down(_v, 32); _v += __shfl_down(_v, 16);            \
    _v += __shfl_down(_v, 8);  _v += __shfl_down(_v, 4);             \
    _v += __shfl_down(_v, 2);  _v += __shfl_down(_v, 1);             \
    if (lane == 0) scr[(idx) * 4 + wave] = _v; }

#define FINALIZE(nv) { __syncthreads();                              \
    if (tid < (nv)) rout[tid] = scr[tid*4] + scr[tid*4+1] + scr[tid*4+2] + scr[tid*4+3]; \
    __syncthreads(); }

    // ---- load tq0 (i-independent) ----
    float tq0[8][3];
    #pragma unroll
    for (int j = 0; j < 8; ++j)
        #pragma unroll
        for (int u = 0; u < 3; ++u)
            tq0[j][u] = H[(size_t)n * JD + j * DD + u * 256 + tid];

    // ---- phase A: dotM0[j,i] = M . tq0, Sq[j], Sq2[j] ----
    #pragma unroll
    for (int j = 0; j < 8; ++j) {
        float s = 0.f, s2 = 0.f;
        #pragma unroll
        for (int u = 0; u < 3; ++u) { float t = tq0[j][u]; s += t; s2 += t * t; }
        WREDUCE(s, 64 + j); WREDUCE(s2, 72 + j);
        #pragma unroll
        for (int i = 0; i < 8; ++i) {
            const float* Mp = hm + (size_t)(j * 8 + i) * DD + tid;
            float a = Mp[0] * tq0[j][0] + Mp[256] * tq0[j][1] + Mp[512] * tq0[j][2];
            WREDUCE(a, j * 8 + i);
        }
    }
    FINALIZE(80);
    if (tid < 64) {                       // p0 -> store w0 = 1/8 + p0
        const int j = tid >> 3;
        float dotM = rout[tid];
        sDotM[tid] = dotM;
        float Sq = rout[64 + j], Sq2v = rout[72 + j];
        float num  = dotM - sMu[tid] * Sq;
        float varq = fmaxf(Sq2v - Sq * Sq * (1.f / 768.f), 0.f);
        float den  = sqrtf(sMc2[tid] * varq) + EPSF;
        sP[tid] = tanhf(num / den) + 0.125f;
    }
    __syncthreads();

    // ---- iter 1: hv1 = sum_i w0 * M ; v1 = squash ----
    float vh[8][3];
    #pragma unroll
    for (int j = 0; j < 8; ++j) {
        float a0 = 0.f, a1 = 0.f, a2 = 0.f;
        #pragma unroll
        for (int i = 0; i < 8; ++i) {
            float w = sP[j * 8 + i];
            const float* Mp = hm + (size_t)(j * 8 + i) * DD + tid;
            a0 += w * Mp[0]; a1 += w * Mp[256]; a2 += w * Mp[512];
        }
        vh[j][0] = a0; vh[j][1] = a1; vh[j][2] = a2;
    }
    #pragma unroll
    for (int j = 0; j < 8; ++j) {
        float s = vh[j][0]*vh[j][0] + vh[j][1]*vh[j][1] + vh[j][2]*vh[j][2];
        WREDUCE(s, j);
    }
    FINALIZE(8);
    float tq1[8][3];
    #pragma unroll
    for (int j = 0; j < 8; ++j) {
        float n2 = rout[j];
        float sc = n2 / ((1.f + n2) * sqrtf(n2 + EPSF));
        #pragma unroll
        for (int u = 0; u < 3; ++u) { vh[j][u] *= sc; tq1[j][u] = 0.5f * (tq0[j][u] + vh[j][u]); }
    }
    // ---- cos1 = M . v1 ; tq1 stats ----
    #pragma unroll
    for (int j = 0; j < 8; ++j) {
        float s = 0.f, s2 = 0.f;
        #pragma unroll
        for (int u = 0; u < 3; ++u) { float t = tq1[j][u]; s += t; s2 += t * t; }
        WREDUCE(s, 64 + j); WREDUCE(s2, 72 + j);
        #pragma unroll
        for (int i = 0; i < 8; ++i) {
            const float* Mp = hm + (size_t)(j * 8 + i) * DD + tid;
            float a = Mp[0] * vh[j][0] + Mp[256] * vh[j][1] + Mp[512] * vh[j][2];
            WREDUCE(a, j * 8 + i);
        }
    }
    FINALIZE(80);
    if (tid < 64) {                       // p1
        const int j = tid >> 3;
        float c1 = rout[tid]; sC1[tid] = c1;
        float dotM = 0.5f * (sDotM[tid] + c1); sDotM[tid] = dotM;
        float Sq = rout[64 + j], Sq2v = rout[72 + j];
        float num  = dotM - sMu[tid] * Sq;
        float varq = fmaxf(Sq2v - Sq * Sq * (1.f / 768.f), 0.f);
        float den  = sqrtf(sMc2[tid] * varq) + EPSF;
        sP[tid] = tanhf(num / den);
    }
    __syncthreads();

    // ---- iter 2: softmax over j of a1 = tq0*c1 ; hv2 ----
    #pragma unroll
    for (int j = 0; j < 8; ++j)
        #pragma unroll
        for (int u = 0; u < 3; ++u) vh[j][u] = 0.f;
    #pragma unroll
    for (int u = 0; u < 3; ++u) {
        #pragma unroll
        for (int i = 0; i < 8; ++i) {
            float x[8], mx = -1e30f;
            #pragma unroll
            for (int j = 0; j < 8; ++j) { x[j] = tq0[j][u] * sC1[j * 8 + i]; mx = fmaxf(mx, x[j]); }
            float es = 0.f;
            #pragma unroll
            for (int j = 0; j < 8; ++j) { x[j] = expf(x[j] - mx); es += x[j]; }
            float inv = 1.f / es;
            #pragma unroll
            for (int j = 0; j < 8; ++j)
                vh[j][u] += (x[j] * inv + sP[j * 8 + i]) * hm[(size_t)(j * 8 + i) * DD + u * 256 + tid];
        }
    }
    #pragma unroll
    for (int j = 0; j < 8; ++j) {
        float s = vh[j][0]*vh[j][0] + vh[j][1]*vh[j][1] + vh[j][2]*vh[j][2];
        WREDUCE(s, j);
    }
    FINALIZE(8);
    #pragma unroll
    for (int j = 0; j < 8; ++j) {
        float n2 = rout[j];
        float sc = n2 / ((1.f + n2) * sqrtf(n2 + EPSF));
        #pragma unroll
        for (int u = 0; u < 3; ++u) vh[j][u] *= sc;          // vh = v2
    }
    // ---- cos2 = M . v2 ; tq2 stats (tq2 = 0.5*(tq1+v2), not stored) ----
    #pragma unroll
    for (int j = 0; j < 8; ++j) {
        float s = 0.f, s2 = 0.f;
        #pragma unroll
        for (int u = 0; u < 3; ++u) { float t = 0.5f * (tq1[j][u] + vh[j][u]); s += t; s2 += t * t; }
        WREDUCE(s, 64 + j); WREDUCE(s2, 72 + j);
        #pragma unroll
        for (int i = 0; i < 8; ++i) {
            const float* Mp = hm + (size_t)(j * 8 + i) * DD + tid;
            float a = Mp[0] * vh[j][0] + Mp[256] * vh[j][1] + Mp[512] * vh[j][2];
            WREDUCE(a, j * 8 + i);
        }
    }
    FINALIZE(80);
    if (tid < 64) {                       // p2
        const int j = tid >> 3;
        float c2 = rout[tid]; sC2[tid] = c2;
        float dotM = 0.5f * (sDotM[tid] + c2); sDotM[tid] = dotM;
        float Sq = rout[64 + j], Sq2v = rout[72 + j];
        float num  = dotM - sMu[tid] * Sq;
        float varq = fmaxf(Sq2v - Sq * Sq * (1.f / 768.f), 0.f);
        float den  = sqrtf(sMc2[tid] * varq) + EPSF;
        sP[tid] = tanhf(num / den);
    }
    __syncthreads();

    // ---- final: softmax over j of a2 = tq0*c1 + tq1*c2 ; hv3 ; squash ; write ----
    #pragma unroll
    for (int j = 0; j < 8; ++j)
        #pragma unroll
        for (int u = 0; u < 3; ++u) vh[j][u] = 0.f;
    #pragma unroll
    for (int u = 0; u < 3; ++u) {
        #pragma unroll
        for (int i = 0; i < 8; ++i) {
            float x[8], mx = -1e30f;
            #pragma unroll
            for (int j = 0; j < 8; ++j) {
                x[j] = tq0[j][u] * sC1[j * 8 + i] + tq1[j][u] * sC2[j * 8 + i];
                mx = fmaxf(mx, x[j]);
            }
            float es = 0.f;
            #pragma unroll
            for (int j = 0; j < 8; ++j) { x[j] = expf(x[j] - mx); es += x[j]; }
            float inv = 1.f / es;
            #pragma unroll
            for (int j = 0; j < 8; ++j)
                vh[j][u] += (x[j] * inv + sP[j * 8 + i]) * hm[(size_t)(j * 8 + i) * DD + u * 256 + tid];
        }
    }
    #pragma unroll
    for (int j = 0; j < 8; ++j) {
        float s = vh[j][0]*vh[j][0] + vh[j][1]*vh[j][1] + vh[j][2]*vh[j][2];
        WREDUCE(s, j);
    }
    FINALIZE(8);
    #pragma unroll
    for (int j = 0; j < 8; ++j) {
        float n2 = rout[j];
        float sc = n2 / ((1.f + n2) * sqrtf(n2 + EPSF));
        #pragma unroll
        for (int u = 0; u < 3; ++u)
            out[(size_t)n * JD + j * DD + u * 256 + tid] = vh[j][u] * sc;
    }
#undef WREDUCE
#undef FINALIZE
}

extern "C" void kernel_launch(void* const* d_in, const int* in_sizes, int n_in,
                              void* d_out, int out_size, void* d_ws, size_t ws_size,
                              hipStream_t stream) {
    const float* m  = (const float*)d_in[0];   // [8,768]
    const float* q  = (const float*)d_in[1];   // [400,768]
    const float* W  = (const float*)d_in[2];   // [1,8,8,768,768]
    const float* b  = (const float*)d_in[3];   // [1,8,8,768]
    const float* Wn = (const float*)d_in[4];   // [768,768]
    float* out = (float*)d_out;
    float* ws  = (float*)d_ws;

    float* mproj = ws + OFF_MPROJ;
    float* H     = ws + OFF_H;
    float* hm    = ws + OFF_HM;
    float* muM   = ws + OFF_MU;
    float* mc2M  = ws + OFF_MC2;

    k_mproj<<<dim3(3, 8), 256, 0, stream>>>(m, Wn, mproj);
    k_gemm<<<dim3(96, 7), 256, 0, stream>>>(q, mproj, W, H);
    k_prep<<<dim3(64), 256, 0, stream>>>(H, b, hm, muM, mc2M);
    k_route<<<dim3(400), 256, 0, stream>>>(H, hm, muM, mc2M, out);
}

// Round 2
// 329.855 us; speedup vs baseline: 2.2796x; 2.2796x over previous
//
#include <hip/hip_runtime.h>
#include <math.h>

#define DD    768
#define NQ    400
#define NROWS 408          // 400 q rows + 8 m_proj rows
#define JD    6144         // J*D = 8*768
#define WSLICE 4718592     // I*D*E = 8*768*768 (stride between j slices of W)
#define EPSF  1e-8f

// ---------------- workspace layout (floats) ----------------
#define OFF_MPROJ 0                       // [8][768]
#define OFF_H     6144                    // [408][6144]
#define OFF_HM    (6144 + 408*6144)       // [64][768]  (j*8+i major)
#define OFF_MU    (OFF_HM + 64*768)       // [64]
#define OFF_MC2   (OFF_MU + 64)           // [64]

// ---------------- kernel 1: m_proj = m @ W_n ----------------
__global__ __launch_bounds__(256) void k_mproj(const float* __restrict__ m,
                                               const float* __restrict__ Wn,
                                               float* __restrict__ mproj)
{
    const int i = blockIdx.y;                       // 0..7
    const int d = blockIdx.x * 256 + threadIdx.x;   // 0..767
    float acc = 0.f;
    #pragma unroll 8
    for (int e = 0; e < DD; ++e)
        acc += m[i*DD + e] * Wn[(size_t)e*DD + d];
    mproj[i*DD + d] = acc;
}

// ---------------- kernel 2: H[x, j*768+d] = sum_e W[j,0,d,e] * X[x,e] ----------------
__global__ __launch_bounds__(256) void k_gemm(const float* __restrict__ q,
                                              const float* __restrict__ mproj,
                                              const float* __restrict__ W,
                                              float* __restrict__ H)
{
    __shared__ float As[32][68];
    __shared__ float Bs[32][68];
    const int tid = threadIdx.x;
    const int tx = tid & 15;
    const int ty = tid >> 4;
    const int c0 = blockIdx.x * 64;     // global col in [0,6144)
    const int m0 = blockIdx.y * 64;     // global row
    const int j  = c0 / DD;
    const int d0 = c0 % DD;             // 64-tiles never straddle a j boundary
    const float* Bbase = W + (size_t)j * WSLICE + (size_t)d0 * DD;  // i = 0 slice
    const int lrow = tid >> 3;          // 0..31
    const int lk   = (tid & 7) << 2;    // 0,4,...,28
    float acc[4][4] = {};

    for (int k0 = 0; k0 < DD; k0 += 32) {
        #pragma unroll
        for (int h = 0; h < 2; ++h) {
            const int r  = lrow + h * 32;
            const int gr = m0 + r;
            float4 av = make_float4(0.f, 0.f, 0.f, 0.f);
            if (gr < NROWS) {
                const float* Arow = (gr < NQ) ? (q + (size_t)gr * DD)
                                              : (mproj + (size_t)(gr - NQ) * DD);
                av = *reinterpret_cast<const float4*>(Arow + k0 + lk);
            }
            As[lk+0][r] = av.x; As[lk+1][r] = av.y; As[lk+2][r] = av.z; As[lk+3][r] = av.w;
            const float4 bv = *reinterpret_cast<const float4*>(Bbase + (size_t)r * DD + k0 + lk);
            Bs[lk+0][r] = bv.x; Bs[lk+1][r] = bv.y; Bs[lk+2][r] = bv.z; Bs[lk+3][r] = bv.w;
        }
        __syncthreads();
        #pragma unroll
        for (int k = 0; k < 32; ++k) {
            const float4 a4 = *reinterpret_cast<const float4*>(&As[k][ty * 4]);
            const float4 b4 = *reinterpret_cast<const float4*>(&Bs[k][tx * 4]);
            acc[0][0] += a4.x * b4.x; acc[0][1] += a4.x * b4.y; acc[0][2] += a4.x * b4.z; acc[0][3] += a4.x * b4.w;
            acc[1][0] += a4.y * b4.x; acc[1][1] += a4.y * b4.y; acc[1][2] += a4.y * b4.z; acc[1][3] += a4.y * b4.w;
            acc[2][0] += a4.z * b4.x; acc[2][1] += a4.z * b4.y; acc[2][2] += a4.z * b4.z; acc[2][3] += a4.z * b4.w;
            acc[3][0] += a4.w * b4.x; acc[3][1] += a4.w * b4.y; acc[3][2] += a4.w * b4.z; acc[3][3] += a4.w * b4.w;
        }
        __syncthreads();
    }
    #pragma unroll
    for (int r = 0; r < 4; ++r) {
        const int gr = m0 + ty * 4 + r;
        if (gr < NROWS) {
            float4 o = make_float4(acc[r][0], acc[r][1], acc[r][2], acc[r][3]);
            *reinterpret_cast<float4*>(H + (size_t)gr * JD + c0 + tx * 4) = o;
        }
    }
}

// ---------------- kernel 3: hat_m + Pearson stats of M rows ----------------
__global__ __launch_bounds__(256) void k_prep(const float* __restrict__ H,
                                              const float* __restrict__ b,
                                              float* __restrict__ hm,
                                              float* __restrict__ muM,
                                              float* __restrict__ mc2M)
{
    const int ji = blockIdx.x;       // j*8+i
    const int j = ji >> 3, i = ji & 7;
    const int tid = threadIdx.x;
    const int lane = tid & 63, wave = tid >> 6;
    __shared__ float scr[4];
    __shared__ float smu;
    float vals[3];
    float s = 0.f;
    #pragma unroll
    for (int u = 0; u < 3; ++u) {
        const int d = u * 256 + tid;
        float x = H[(size_t)(NQ + i) * JD + j * DD + d] + b[(size_t)ji * DD + d];
        hm[(size_t)ji * DD + d] = x;
        vals[u] = x;
        s += x;
    }
    #pragma unroll
    for (int off = 32; off; off >>= 1) s += __shfl_down(s, off);
    if (lane == 0) scr[wave] = s;
    __syncthreads();
    if (tid == 0) smu = (scr[0] + scr[1] + scr[2] + scr[3]) * (1.f / 768.f);
    __syncthreads();
    const float mu = smu;
    float s2 = 0.f;
    #pragma unroll
    for (int u = 0; u < 3; ++u) { float c = vals[u] - mu; s2 += c * c; }
    __syncthreads();
    #pragma unroll
    for (int off = 32; off; off >>= 1) s2 += __shfl_down(s2, off);
    if (lane == 0) scr[wave] = s2;
    __syncthreads();
    if (tid == 0) { muM[ji] = mu; mc2M[ji] = scr[0] + scr[1] + scr[2] + scr[3]; }
}

// ---------------- kernel 4: fused routing, one block per n, 768 threads ----------------
// thread tid owns dimension d = tid for all 8 capsules j.
// 64-way dot reductions (M[ji] . vec[j]) are done by staging vec in LDS and
// splitting the 64 rows across the 12 waves (wave-local shuffle reduce only).
__global__ __launch_bounds__(768) void k_route(const float* __restrict__ H,
                                               const float* __restrict__ hm,
                                               const float* __restrict__ muM,
                                               const float* __restrict__ mc2M,
                                               float* __restrict__ out)
{
    const int n = blockIdx.x;
    const int tid = threadIdx.x;              // d
    const int lane = tid & 63, wave = tid >> 6;   // 12 waves
    __shared__ __align__(16) float sV[8][768];
    __shared__ float scr[16][12];
    __shared__ float rstat[16];
    __shared__ float sDot[64];
    __shared__ float sMu[64], sMc2[64], sP[64], sC1[64], sC2[64], sDotM[64];

    if (tid < 64) { sMu[tid] = muM[tid]; sMc2[tid] = mc2M[tid]; }

#define WRED(val, idx) { float _v = (val);                           \
    _v += __shfl_down(_v, 32); _v += __shfl_down(_v, 16);            \
    _v += __shfl_down(_v, 8);  _v += __shfl_down(_v, 4);             \
    _v += __shfl_down(_v, 2);  _v += __shfl_down(_v, 1);             \
    if (lane == 0) scr[(idx)][wave] = _v; }

#define FIN(nv) { if (tid < (nv)) { float _s = 0.f;                  \
    _Pragma("unroll")                                                \
    for (int _w = 0; _w < 12; ++_w) _s += scr[tid][_w];              \
    rstat[tid] = _s; } }

#define DOTLOOP() for (int t = wave; t < 64; t += 12) {              \
        const int _j = t >> 3;                                       \
        const float* Mrow = hm + (size_t)t * DD;                     \
        float acc = 0.f;                                             \
        _Pragma("unroll")                                            \
        for (int c = 0; c < 3; ++c) {                                \
            const int dd = c * 256 + lane * 4;                       \
            const float4 mv = *reinterpret_cast<const float4*>(Mrow + dd);       \
            const float4 vv = *reinterpret_cast<const float4*>(&sV[_j][dd]);     \
            acc += mv.x*vv.x + mv.y*vv.y + mv.z*vv.z + mv.w*vv.w;    \
        }                                                            \
        acc += __shfl_down(acc, 32); acc += __shfl_down(acc, 16);    \
        acc += __shfl_down(acc, 8);  acc += __shfl_down(acc, 4);     \
        acc += __shfl_down(acc, 2);  acc += __shfl_down(acc, 1);     \
        if (lane == 0) sDot[t] = acc;                                \
    }

#define PEARSON(PEXTRA) { const int j = tid >> 3;                    \
        float Sq = rstat[j], Sq2v = rstat[8 + j];                    \
        float num  = sDotM[tid] - sMu[tid] * Sq;                     \
        float varq = fmaxf(Sq2v - Sq * Sq * (1.f / 768.f), 0.f);     \
        float den  = sqrtf(sMc2[tid] * varq) + EPSF;                 \
        sP[tid] = tanhf(num / den) PEXTRA; }

    // ---- load tq0 (i-independent), stage in LDS, stats ----
    float tq0[8], tq1[8], vh[8];
    #pragma unroll
    for (int j = 0; j < 8; ++j) {
        tq0[j] = H[(size_t)n * JD + j * DD + tid];
        sV[j][tid] = tq0[j];
    }
    #pragma unroll
    for (int j = 0; j < 8; ++j) { WRED(tq0[j], j); WRED(tq0[j] * tq0[j], 8 + j); }
    __syncthreads();
    DOTLOOP();                                     // sDot = M . tq0
    FIN(16);
    __syncthreads();
    if (tid < 64) { sDotM[tid] = sDot[tid]; PEARSON(+ 0.125f); }   // w0 = 1/8 + p0
    __syncthreads();

    // ---- iter 1: hv1 = sum_i w0 * M ; squash ----
    #pragma unroll
    for (int j = 0; j < 8; ++j) {
        float a = 0.f;
        #pragma unroll
        for (int i = 0; i < 8; ++i)
            a += sP[j * 8 + i] * hm[(size_t)(j * 8 + i) * DD + tid];
        vh[j] = a;
        WRED(a * a, j);
    }
    __syncthreads();
    FIN(8);
    __syncthreads();
    #pragma unroll
    for (int j = 0; j < 8; ++j) {
        float n2 = rstat[j];
        float sc = n2 / ((1.f + n2) * sqrtf(n2 + EPSF));
        vh[j] *= sc;                               // vh = v1
        tq1[j] = 0.5f * (tq0[j] + vh[j]);
        sV[j][tid] = vh[j];
    }
    #pragma unroll
    for (int j = 0; j < 8; ++j) { WRED(tq1[j], j); WRED(tq1[j] * tq1[j], 8 + j); }
    __syncthreads();
    DOTLOOP();                                     // sDot = M . v1
    FIN(16);
    __syncthreads();
    if (tid < 64) {
        float c1 = sDot[tid]; sC1[tid] = c1;
        sDotM[tid] = 0.5f * (sDotM[tid] + c1);
        PEARSON();
    }
    __syncthreads();

    // ---- iter 2: softmax over j of a1 = tq0*c1 ; hv2 ----
    #pragma unroll
    for (int j = 0; j < 8; ++j) vh[j] = 0.f;
    #pragma unroll
    for (int i = 0; i < 8; ++i) {
        float x[8], mx = -1e30f;
        #pragma unroll
        for (int j = 0; j < 8; ++j) { x[j] = tq0[j] * sC1[j * 8 + i]; mx = fmaxf(mx, x[j]); }
        float es = 0.f;
        #pragma unroll
        for (int j = 0; j < 8; ++j) { x[j] = expf(x[j] - mx); es += x[j]; }
        float inv = 1.f / es;
        #pragma unroll
        for (int j = 0; j < 8; ++j)
            vh[j] += (x[j] * inv + sP[j * 8 + i]) * hm[(size_t)(j * 8 + i) * DD + tid];
    }
    #pragma unroll
    for (int j = 0; j < 8; ++j) WRED(vh[j] * vh[j], j);
    __syncthreads();
    FIN(8);
    __syncthreads();
    #pragma unroll
    for (int j = 0; j < 8; ++j) {
        float n2 = rstat[j];
        float sc = n2 / ((1.f + n2) * sqrtf(n2 + EPSF));
        vh[j] *= sc;                               // vh = v2
        sV[j][tid] = vh[j];
        float t2 = 0.5f * (tq1[j] + vh[j]);        // tq2 (stats only)
        tq1[j] = t2;                               // reuse reg: tq1 now holds tq2? NO - needed in final softmax!
    }
    // NOTE: final softmax needs original tq1 — undo the aliasing above by
    // keeping tq2 stats computed from t2 before overwrite. Recompute properly:
    // (we stored tq2 into tq1; final softmax uses tq1_orig = 2*tq2 - v2... )
    // Simpler: recover tq1_orig = 2*tq2 - v2.
    #pragma unroll
    for (int j = 0; j < 8; ++j) { WRED(tq1[j], j); WRED(tq1[j] * tq1[j], 8 + j); }
    __syncthreads();
    DOTLOOP();                                     // sDot = M . v2
    FIN(16);
    __syncthreads();
    if (tid < 64) {
        float c2 = sDot[tid]; sC2[tid] = c2;
        sDotM[tid] = 0.5f * (sDotM[tid] + c2);
        PEARSON();
    }
    __syncthreads();
    #pragma unroll
    for (int j = 0; j < 8; ++j) tq1[j] = 2.f * tq1[j] - vh[j];   // restore tq1_orig

    // ---- final: softmax over j of a2 = tq0*c1 + tq1*c2 ; hv3 ; squash ; write ----
    #pragma unroll
    for (int j = 0; j < 8; ++j) vh[j] = 0.f;
    #pragma unroll
    for (int i = 0; i < 8; ++i) {
        float x[8], mx = -1e30f;
        #pragma unroll
        for (int j = 0; j < 8; ++j) {
            x[j] = tq0[j] * sC1[j * 8 + i] + tq1[j] * sC2[j * 8 + i];
            mx = fmaxf(mx, x[j]);
        }
        float es = 0.f;
        #pragma unroll
        for (int j = 0; j < 8; ++j) { x[j] = expf(x[j] - mx); es += x[j]; }
        float inv = 1.f / es;
        #pragma unroll
        for (int j = 0; j < 8; ++j)
            vh[j] += (x[j] * inv + sP[j * 8 + i]) * hm[(size_t)(j * 8 + i) * DD + tid];
    }
    #pragma unroll
    for (int j = 0; j < 8; ++j) WRED(vh[j] * vh[j], j);
    __syncthreads();
    FIN(8);
    __syncthreads();
    #pragma unroll
    for (int j = 0; j < 8; ++j) {
        float n2 = rstat[j];
        float sc = n2 / ((1.f + n2) * sqrtf(n2 + EPSF));
        out[(size_t)n * JD + j * DD + tid] = vh[j] * sc;
    }
#undef WRED
#undef FIN
#undef DOTLOOP
#undef PEARSON
}

extern "C" void kernel_launch(void* const* d_in, const int* in_sizes, int n_in,
                              void* d_out, int out_size, void* d_ws, size_t ws_size,
                              hipStream_t stream) {
    const float* m  = (const float*)d_in[0];   // [8,768]
    const float* q  = (const float*)d_in[1];   // [400,768]
    const float* W  = (const float*)d_in[2];   // [1,8,8,768,768]
    const float* b  = (const float*)d_in[3];   // [1,8,8,768]
    const float* Wn = (const float*)d_in[4];   // [768,768]
    float* out = (float*)d_out;
    float* ws  = (float*)d_ws;

    float* mproj = ws + OFF_MPROJ;
    float* H     = ws + OFF_H;
    float* hm    = ws + OFF_HM;
    float* muM   = ws + OFF_MU;
    float* mc2M  = ws + OFF_MC2;

    k_mproj<<<dim3(3, 8), 256, 0, stream>>>(m, Wn, mproj);
    k_gemm<<<dim3(96, 7), 256, 0, stream>>>(q, mproj, W, H);
    k_prep<<<dim3(64), 256, 0, stream>>>(H, b, hm, muM, mc2M);
    k_route<<<dim3(400), 768, 0, stream>>>(H, hm, muM, mc2M, out);
}

// Round 3
// 326.504 us; speedup vs baseline: 2.3030x; 1.0103x over previous
//
#include <hip/hip_runtime.h>
#include <math.h>

#define DD    768
#define NQ    400
#define NROWS 408          // 400 q rows + 8 m_proj rows
#define JD    6144         // J*D = 8*768
#define WSLICE 4718592     // I*D*E = 8*768*768 (stride between j slices of W)
#define EPSF  1e-8f

// ---------------- workspace layout (floats) ----------------
#define OFF_MPROJ 0                       // [8][768]
#define OFF_H     6144                    // [408][6144]
#define OFF_HM    (6144 + 408*6144)       // [64][768]  (j*8+i major)
#define OFF_MU    (OFF_HM + 64*768)       // [64]
#define OFF_MC2   (OFF_MU + 64)           // [64]

// ---------------- kernel 1: m_proj = m @ W_n ----------------
__global__ __launch_bounds__(256) void k_mproj(const float* __restrict__ m,
                                               const float* __restrict__ Wn,
                                               float* __restrict__ mproj)
{
    const int i = blockIdx.y;                       // 0..7
    const int d = blockIdx.x * 256 + threadIdx.x;   // 0..767
    float acc = 0.f;
    #pragma unroll 8
    for (int e = 0; e < DD; ++e)
        acc += m[i*DD + e] * Wn[(size_t)e*DD + d];
    mproj[i*DD + d] = acc;
}

// ---------------- kernel 2: H[x, j*768+d] = sum_e W[j,0,d,e] * X[x,e] ----------------
__global__ __launch_bounds__(256) void k_gemm(const float* __restrict__ q,
                                              const float* __restrict__ mproj,
                                              const float* __restrict__ W,
                                              float* __restrict__ H)
{
    __shared__ float As[32][68];
    __shared__ float Bs[32][68];
    const int tid = threadIdx.x;
    const int tx = tid & 15;
    const int ty = tid >> 4;
    const int c0 = blockIdx.x * 64;     // global col in [0,6144)
    const int m0 = blockIdx.y * 64;     // global row
    const int j  = c0 / DD;
    const int d0 = c0 % DD;             // 64-tiles never straddle a j boundary
    const float* Bbase = W + (size_t)j * WSLICE + (size_t)d0 * DD;  // i = 0 slice
    const int lrow = tid >> 3;          // 0..31
    const int lk   = (tid & 7) << 2;    // 0,4,...,28
    float acc[4][4] = {};

    for (int k0 = 0; k0 < DD; k0 += 32) {
        #pragma unroll
        for (int h = 0; h < 2; ++h) {
            const int r  = lrow + h * 32;
            const int gr = m0 + r;
            float4 av = make_float4(0.f, 0.f, 0.f, 0.f);
            if (gr < NROWS) {
                const float* Arow = (gr < NQ) ? (q + (size_t)gr * DD)
                                              : (mproj + (size_t)(gr - NQ) * DD);
                av = *reinterpret_cast<const float4*>(Arow + k0 + lk);
            }
            As[lk+0][r] = av.x; As[lk+1][r] = av.y; As[lk+2][r] = av.z; As[lk+3][r] = av.w;
            const float4 bv = *reinterpret_cast<const float4*>(Bbase + (size_t)r * DD + k0 + lk);
            Bs[lk+0][r] = bv.x; Bs[lk+1][r] = bv.y; Bs[lk+2][r] = bv.z; Bs[lk+3][r] = bv.w;
        }
        __syncthreads();
        #pragma unroll
        for (int k = 0; k < 32; ++k) {
            const float4 a4 = *reinterpret_cast<const float4*>(&As[k][ty * 4]);
            const float4 b4 = *reinterpret_cast<const float4*>(&Bs[k][tx * 4]);
            acc[0][0] += a4.x * b4.x; acc[0][1] += a4.x * b4.y; acc[0][2] += a4.x * b4.z; acc[0][3] += a4.x * b4.w;
            acc[1][0] += a4.y * b4.x; acc[1][1] += a4.y * b4.y; acc[1][2] += a4.y * b4.z; acc[1][3] += a4.y * b4.w;
            acc[2][0] += a4.z * b4.x; acc[2][1] += a4.z * b4.y; acc[2][2] += a4.z * b4.z; acc[2][3] += a4.z * b4.w;
            acc[3][0] += a4.w * b4.x; acc[3][1] += a4.w * b4.y; acc[3][2] += a4.w * b4.z; acc[3][3] += a4.w * b4.w;
        }
        __syncthreads();
    }
    #pragma unroll
    for (int r = 0; r < 4; ++r) {
        const int gr = m0 + ty * 4 + r;
        if (gr < NROWS) {
            float4 o = make_float4(acc[r][0], acc[r][1], acc[r][2], acc[r][3]);
            *reinterpret_cast<float4*>(H + (size_t)gr * JD + c0 + tx * 4) = o;
        }
    }
}

// ---------------- kernel 3: hat_m + Pearson stats of M rows ----------------
__global__ __launch_bounds__(256) void k_prep(const float* __restrict__ H,
                                              const float* __restrict__ b,
                                              float* __restrict__ hm,
                                              float* __restrict__ muM,
                                              float* __restrict__ mc2M)
{
    const int ji = blockIdx.x;       // j*8+i
    const int j = ji >> 3, i = ji & 7;
    const int tid = threadIdx.x;
    const int lane = tid & 63, wave = tid >> 6;
    __shared__ float scr[4];
    __shared__ float smu;
    float vals[3];
    float s = 0.f;
    #pragma unroll
    for (int u = 0; u < 3; ++u) {
        const int d = u * 256 + tid;
        float x = H[(size_t)(NQ + i) * JD + j * DD + d] + b[(size_t)ji * DD + d];
        hm[(size_t)ji * DD + d] = x;
        vals[u] = x;
        s += x;
    }
    #pragma unroll
    for (int off = 32; off; off >>= 1) s += __shfl_down(s, off);
    if (lane == 0) scr[wave] = s;
    __syncthreads();
    if (tid == 0) smu = (scr[0] + scr[1] + scr[2] + scr[3]) * (1.f / 768.f);
    __syncthreads();
    const float mu = smu;
    float s2 = 0.f;
    #pragma unroll
    for (int u = 0; u < 3; ++u) { float c = vals[u] - mu; s2 += c * c; }
    __syncthreads();
    #pragma unroll
    for (int off = 32; off; off >>= 1) s2 += __shfl_down(s2, off);
    if (lane == 0) scr[wave] = s2;
    __syncthreads();
    if (tid == 0) { muM[ji] = mu; mc2M[ji] = scr[0] + scr[1] + scr[2] + scr[3]; }
}

// ---------------- kernel 4: fused routing, one block per n, 768 threads ----------------
// All per-thread multi-capsule state is EXPLICIT SCALARS (no arrays -> no scratch).
// Cross-thread vectors live in one reusable LDS buffer sVv (tq0 -> v1 -> v2).
#define FOR8(M) M(0) M(1) M(2) M(3) M(4) M(5) M(6) M(7)

__global__ __launch_bounds__(768, 3) void k_route(const float* __restrict__ H,
                                                  const float* __restrict__ hm,
                                                  const float* __restrict__ muM,
                                                  const float* __restrict__ mc2M,
                                                  float* __restrict__ out)
{
    const int n = blockIdx.x;
    const int tid = threadIdx.x;                  // d
    const int lane = tid & 63, wave = tid >> 6;   // 12 waves
    __shared__ __align__(16) float sVv[8][768];
    __shared__ float scr[16][12];
    __shared__ float rstat[16];
    __shared__ float sDot[64];
    __shared__ float sMu[64], sMc2[64], sP[64], sC1[64], sC2[64], sDotM[64];

    if (tid < 64) { sMu[tid] = muM[tid]; sMc2[tid] = mc2M[tid]; }

#define WRED(val, idx) { float _v = (val);                           \
    _v += __shfl_down(_v, 32); _v += __shfl_down(_v, 16);            \
    _v += __shfl_down(_v, 8);  _v += __shfl_down(_v, 4);             \
    _v += __shfl_down(_v, 2);  _v += __shfl_down(_v, 1);             \
    if (lane == 0) scr[(idx)][wave] = _v; }

#define FIN(nv) { if (tid < (nv)) { float _s = 0.f;                  \
    _Pragma("unroll")                                                \
    for (int _w = 0; _w < 12; ++_w) _s += scr[tid][_w];              \
    rstat[tid] = _s; } }

#define DOTLOOP() for (int t = wave; t < 64; t += 12) {              \
        const int _j = t >> 3;                                       \
        const float* Mrow = hm + (size_t)t * DD;                     \
        float acc = 0.f;                                             \
        _Pragma("unroll")                                            \
        for (int c = 0; c < 3; ++c) {                                \
            const int dd = c * 256 + lane * 4;                       \
            const float4 mv = *reinterpret_cast<const float4*>(Mrow + dd);       \
            const float4 vv = *reinterpret_cast<const float4*>(&sVv[_j][dd]);    \
            acc += mv.x*vv.x + mv.y*vv.y + mv.z*vv.z + mv.w*vv.w;    \
        }                                                            \
        acc += __shfl_down(acc, 32); acc += __shfl_down(acc, 16);    \
        acc += __shfl_down(acc, 8);  acc += __shfl_down(acc, 4);     \
        acc += __shfl_down(acc, 2);  acc += __shfl_down(acc, 1);     \
        if (lane == 0) sDot[t] = acc;                                \
    }

#define PEARSON(PEXTRA) { const int j = tid >> 3;                    \
        float Sq = rstat[j], Sq2v = rstat[8 + j];                    \
        float num  = sDotM[tid] - sMu[tid] * Sq;                     \
        float varq = fmaxf(Sq2v - Sq * Sq * (1.f / 768.f), 0.f);     \
        float den  = sqrtf(sMc2[tid] * varq) + EPSF;                 \
        sP[tid] = tanhf(num / den) PEXTRA; }

    // ---- per-thread scalar state ----
#define DECL(k) float t0_##k, t1_##k, vh_##k;
    FOR8(DECL)
#undef DECL

    const float* Hn = H + (size_t)n * JD + tid;
    // ---- phase 0: load tq0, stage in LDS, stats, dot0, p0 ----
#define LOADT0(k) t0_##k = Hn[k * DD]; sVv[k][tid] = t0_##k;
    FOR8(LOADT0)
#undef LOADT0
#define STAT0(k) WRED(t0_##k, k); WRED(t0_##k * t0_##k, 8 + k);
    FOR8(STAT0)
#undef STAT0
    __syncthreads();
    DOTLOOP();                                     // sDot = M . tq0
    FIN(16);
    __syncthreads();
    if (tid < 64) { sDotM[tid] = sDot[tid]; PEARSON(+ 0.125f); }   // w0 = 1/8 + p0
    __syncthreads();

    // ---- iter 1: hv1 = sum_i w0 * M ; squash -> v1 ; tq1 ----
#define HV1(k) { float a = 0.f;                                      \
        _Pragma("unroll")                                            \
        for (int i = 0; i < 8; ++i)                                  \
            a += sP[k * 8 + i] * hm[(size_t)(k * 8 + i) * DD + tid]; \
        vh_##k = a; WRED(a * a, k); }
    FOR8(HV1)
#undef HV1
    __syncthreads();
    FIN(8);
    __syncthreads();
#define SQ1(k) { float n2 = rstat[k];                                \
        float sc = n2 / ((1.f + n2) * sqrtf(n2 + EPSF));             \
        vh_##k *= sc; t1_##k = 0.5f * (t0_##k + vh_##k);             \
        sVv[k][tid] = vh_##k; }
    FOR8(SQ1)
#undef SQ1
#define STAT1(k) WRED(t1_##k, k); WRED(t1_##k * t1_##k, 8 + k);
    FOR8(STAT1)
#undef STAT1
    __syncthreads();
    DOTLOOP();                                     // sDot = M . v1
    FIN(16);
    __syncthreads();
    if (tid < 64) {
        float c1 = sDot[tid]; sC1[tid] = c1;
        sDotM[tid] = 0.5f * (sDotM[tid] + c1);
        PEARSON();
    }
    __syncthreads();

    // ---- iter 2: softmax over j of a1 = tq0*c1 ; hv2 ; squash -> v2 ----
#define ZV(k) vh_##k = 0.f;
    FOR8(ZV)
#undef ZV
    #pragma unroll
    for (int i = 0; i < 8; ++i) {
#define XA(k) float x##k = t0_##k * sC1[k * 8 + i];
        FOR8(XA)
#undef XA
        float mx = fmaxf(fmaxf(fmaxf(x0, x1), fmaxf(x2, x3)),
                         fmaxf(fmaxf(x4, x5), fmaxf(x6, x7)));
#define XE(k) x##k = expf(x##k - mx);
        FOR8(XE)
#undef XE
        float inv = 1.f / (x0 + x1 + x2 + x3 + x4 + x5 + x6 + x7);
#define XACC(k) vh_##k += (x##k * inv + sP[k * 8 + i]) * hm[(size_t)(k * 8 + i) * DD + tid];
        FOR8(XACC)
#undef XACC
    }
#define NRM(k) WRED(vh_##k * vh_##k, k);
    FOR8(NRM)
#undef NRM
    __syncthreads();
    FIN(8);
    __syncthreads();
#define SQ2(k) { float n2 = rstat[k];                                \
        float sc = n2 / ((1.f + n2) * sqrtf(n2 + EPSF));             \
        vh_##k *= sc; sVv[k][tid] = vh_##k; }
    FOR8(SQ2)
#undef SQ2
    // tq2 = 0.5*(tq1 + v2): stats only
#define STAT2(k) { float t2 = 0.5f * (t1_##k + vh_##k);              \
        WRED(t2, k); WRED(t2 * t2, 8 + k); }
    FOR8(STAT2)
#undef STAT2
    __syncthreads();
    DOTLOOP();                                     // sDot = M . v2
    FIN(16);
    __syncthreads();
    if (tid < 64) {
        float c2 = sDot[tid]; sC2[tid] = c2;
        sDotM[tid] = 0.5f * (sDotM[tid] + c2);
        PEARSON();
    }
    __syncthreads();

    // ---- final: softmax over j of a2 = tq0*c1 + tq1*c2 ; hv3 ; squash ; write ----
#define ZV(k) vh_##k = 0.f;
    FOR8(ZV)
#undef ZV
    #pragma unroll
    for (int i = 0; i < 8; ++i) {
#define XA(k) float x##k = t0_##k * sC1[k * 8 + i] + t1_##k * sC2[k * 8 + i];
        FOR8(XA)
#undef XA
        float mx = fmaxf(fmaxf(fmaxf(x0, x1), fmaxf(x2, x3)),
                         fmaxf(fmaxf(x4, x5), fmaxf(x6, x7)));
#define XE(k) x##k = expf(x##k - mx);
        FOR8(XE)
#undef XE
        float inv = 1.f / (x0 + x1 + x2 + x3 + x4 + x5 + x6 + x7);
#define XACC(k) vh_##k += (x##k * inv + sP[k * 8 + i]) * hm[(size_t)(k * 8 + i) * DD + tid];
        FOR8(XACC)
#undef XACC
    }
#define NRM(k) WRED(vh_##k * vh_##k, k);
    FOR8(NRM)
#undef NRM
    __syncthreads();
    FIN(8);
    __syncthreads();
    float* On = out + (size_t)n * JD + tid;
#define WOUT(k) { float n2 = rstat[k];                               \
        float sc = n2 / ((1.f + n2) * sqrtf(n2 + EPSF));             \
        On[k * DD] = vh_##k * sc; }
    FOR8(WOUT)
#undef WOUT
#undef WRED
#undef FIN
#undef DOTLOOP
#undef PEARSON
}

extern "C" void kernel_launch(void* const* d_in, const int* in_sizes, int n_in,
                              void* d_out, int out_size, void* d_ws, size_t ws_size,
                              hipStream_t stream) {
    const float* m  = (const float*)d_in[0];   // [8,768]
    const float* q  = (const float*)d_in[1];   // [400,768]
    const float* W  = (const float*)d_in[2];   // [1,8,8,768,768]
    const float* b  = (const float*)d_in[3];   // [1,8,8,768]
    const float* Wn = (const float*)d_in[4];   // [768,768]
    float* out = (float*)d_out;
    float* ws  = (float*)d_ws;

    float* mproj = ws + OFF_MPROJ;
    float* H     = ws + OFF_H;
    float* hm    = ws + OFF_HM;
    float* muM   = ws + OFF_MU;
    float* mc2M  = ws + OFF_MC2;

    k_mproj<<<dim3(3, 8), 256, 0, stream>>>(m, Wn, mproj);
    k_gemm<<<dim3(96, 7), 256, 0, stream>>>(q, mproj, W, H);
    k_prep<<<dim3(64), 256, 0, stream>>>(H, b, hm, muM, mc2M);
    k_route<<<dim3(400), 768, 0, stream>>>(H, hm, muM, mc2M, out);
}

// Round 4
// 306.249 us; speedup vs baseline: 2.4553x; 1.0661x over previous
//
#include <hip/hip_runtime.h>
#include <math.h>

#define DD    768
#define NQ    400
#define NROWS 408          // 400 q rows + 8 m_proj rows
#define JD    6144         // J*D = 8*768
#define WSLICE 4718592     // I*D*E = 8*768*768 (stride between j slices of W)
#define EPSF  1e-8f

// ---------------- workspace layout (floats) ----------------
#define OFF_MPROJ 0                       // [8][768]
#define OFF_H     6144                    // [408][6144]
#define OFF_HM    (OFF_H + 408*6144)      // [64][768]  (j*8+i major)
#define OFF_MU    (OFF_HM + 64*768)       // [64]
#define OFF_MC2   (OFF_MU + 64)           // [64]
#define OFF_G     (OFF_MC2 + 64)          // [64][8]  Gram
#define OFF_DMQ   (OFF_G + 512)           // [400][64] dot(M_ji, q'_nj)
#define OFF_SQ0   (OFF_DMQ + 400*64)      // [400][8]  sum(q'_nj)
#define OFF_SQ20  (OFF_SQ0 + 400*8)       // [400][8]  sumsq(q'_nj)

#define FOR8(M) M(0) M(1) M(2) M(3) M(4) M(5) M(6) M(7)

// ---------------- kernel 1: m_proj = m @ W_n ----------------
__global__ __launch_bounds__(256) void k_mproj(const float* __restrict__ m,
                                               const float* __restrict__ Wn,
                                               float* __restrict__ mproj)
{
    const int i = blockIdx.y;
    const int d = blockIdx.x * 256 + threadIdx.x;
    float acc = 0.f;
    #pragma unroll 8
    for (int e = 0; e < DD; ++e)
        acc += m[i*DD + e] * Wn[(size_t)e*DD + d];
    mproj[i*DD + d] = acc;
}

// ---------------- kernel 2: H[x, j*768+d] = sum_e W[j,0,d,e] * X[x,e] ----------------
__global__ __launch_bounds__(256) void k_gemm(const float* __restrict__ q,
                                              const float* __restrict__ mproj,
                                              const float* __restrict__ W,
                                              float* __restrict__ H)
{
    __shared__ float As[32][68];
    __shared__ float Bs[32][68];
    const int tid = threadIdx.x;
    const int tx = tid & 15;
    const int ty = tid >> 4;
    const int c0 = blockIdx.x * 64;
    const int m0 = blockIdx.y * 64;
    const int j  = c0 / DD;
    const int d0 = c0 % DD;
    const float* Bbase = W + (size_t)j * WSLICE + (size_t)d0 * DD;
    const int lrow = tid >> 3;
    const int lk   = (tid & 7) << 2;
    float acc[4][4] = {};

    for (int k0 = 0; k0 < DD; k0 += 32) {
        #pragma unroll
        for (int h = 0; h < 2; ++h) {
            const int r  = lrow + h * 32;
            const int gr = m0 + r;
            float4 av = make_float4(0.f, 0.f, 0.f, 0.f);
            if (gr < NROWS) {
                const float* Arow = (gr < NQ) ? (q + (size_t)gr * DD)
                                              : (mproj + (size_t)(gr - NQ) * DD);
                av = *reinterpret_cast<const float4*>(Arow + k0 + lk);
            }
            As[lk+0][r] = av.x; As[lk+1][r] = av.y; As[lk+2][r] = av.z; As[lk+3][r] = av.w;
            const float4 bv = *reinterpret_cast<const float4*>(Bbase + (size_t)r * DD + k0 + lk);
            Bs[lk+0][r] = bv.x; Bs[lk+1][r] = bv.y; Bs[lk+2][r] = bv.z; Bs[lk+3][r] = bv.w;
        }
        __syncthreads();
        #pragma unroll
        for (int k = 0; k < 32; ++k) {
            const float4 a4 = *reinterpret_cast<const float4*>(&As[k][ty * 4]);
            const float4 b4 = *reinterpret_cast<const float4*>(&Bs[k][tx * 4]);
            acc[0][0] += a4.x * b4.x; acc[0][1] += a4.x * b4.y; acc[0][2] += a4.x * b4.z; acc[0][3] += a4.x * b4.w;
            acc[1][0] += a4.y * b4.x; acc[1][1] += a4.y * b4.y; acc[1][2] += a4.y * b4.z; acc[1][3] += a4.y * b4.w;
            acc[2][0] += a4.z * b4.x; acc[2][1] += a4.z * b4.y; acc[2][2] += a4.z * b4.z; acc[2][3] += a4.z * b4.w;
            acc[3][0] += a4.w * b4.x; acc[3][1] += a4.w * b4.y; acc[3][2] += a4.w * b4.z; acc[3][3] += a4.w * b4.w;
        }
        __syncthreads();
    }
    #pragma unroll
    for (int r = 0; r < 4; ++r) {
        const int gr = m0 + ty * 4 + r;
        if (gr < NROWS) {
            float4 o = make_float4(acc[r][0], acc[r][1], acc[r][2], acc[r][3]);
            *reinterpret_cast<float4*>(H + (size_t)gr * JD + c0 + tx * 4) = o;
        }
    }
}

// ---------------- kernel 3: hat_m + Pearson stats of M rows ----------------
__global__ __launch_bounds__(256) void k_prep(const float* __restrict__ H,
                                              const float* __restrict__ b,
                                              float* __restrict__ hm,
                                              float* __restrict__ muM,
                                              float* __restrict__ mc2M)
{
    const int ji = blockIdx.x;
    const int j = ji >> 3, i = ji & 7;
    const int tid = threadIdx.x;
    const int lane = tid & 63, wave = tid >> 6;
    __shared__ float scr[4];
    __shared__ float smu;
    float vals[3];
    float s = 0.f;
    #pragma unroll
    for (int u = 0; u < 3; ++u) {
        const int d = u * 256 + tid;
        float x = H[(size_t)(NQ + i) * JD + j * DD + d] + b[(size_t)ji * DD + d];
        hm[(size_t)ji * DD + d] = x;
        vals[u] = x;
        s += x;
    }
    #pragma unroll
    for (int off = 32; off; off >>= 1) s += __shfl_down(s, off);
    if (lane == 0) scr[wave] = s;
    __syncthreads();
    if (tid == 0) smu = (scr[0] + scr[1] + scr[2] + scr[3]) * (1.f / 768.f);
    __syncthreads();
    const float mu = smu;
    float s2 = 0.f;
    #pragma unroll
    for (int u = 0; u < 3; ++u) { float c = vals[u] - mu; s2 += c * c; }
    __syncthreads();
    #pragma unroll
    for (int off = 32; off; off >>= 1) s2 += __shfl_down(s2, off);
    if (lane == 0) scr[wave] = s2;
    __syncthreads();
    if (tid == 0) { muM[ji] = mu; mc2M[ji] = scr[0] + scr[1] + scr[2] + scr[3]; }
}

// ---------------- kernel 3b: Gram matrix G[ji][i'] = M_ji . M_ji' ----------------
__global__ __launch_bounds__(256) void k_gram(const float* __restrict__ hm,
                                              float* __restrict__ G)
{
    const int ji = blockIdx.x;          // 0..63
    const int j = ji >> 3;
    const int tid = threadIdx.x;
    const int lane = tid & 63, wave = tid >> 6;
    __shared__ float scr[8][4];
    const float a0 = hm[(size_t)ji*DD + tid];
    const float a1 = hm[(size_t)ji*DD + 256 + tid];
    const float a2 = hm[(size_t)ji*DD + 512 + tid];
#define GDOT(k) { const float* Bp = hm + (size_t)(j*8 + k)*DD + tid;             \
        float acc = a0*Bp[0] + a1*Bp[256] + a2*Bp[512];                          \
        acc += __shfl_down(acc, 32); acc += __shfl_down(acc, 16);                \
        acc += __shfl_down(acc, 8);  acc += __shfl_down(acc, 4);                 \
        acc += __shfl_down(acc, 2);  acc += __shfl_down(acc, 1);                 \
        if (lane == 0) scr[k][wave] = acc; }
    FOR8(GDOT)
#undef GDOT
    __syncthreads();
    if (tid < 8) G[ji*8 + tid] = scr[tid][0] + scr[tid][1] + scr[tid][2] + scr[tid][3];
}

// ---------------- kernel 3c: per-n dots dmq[n][ji] = M_ji . q'_nj + q' stats ----
__global__ __launch_bounds__(256) void k_dots(const float* __restrict__ H,
                                              const float* __restrict__ hm,
                                              float* __restrict__ dmq,
                                              float* __restrict__ Sq0v,
                                              float* __restrict__ Sq20v)
{
    const int j = blockIdx.x;           // 0..7
    const int tile = blockIdx.y;        // 0..7 (50 n each)
    const int tid = threadIdx.x;
    const int lane = tid & 63, wave = tid >> 6;   // 4 waves
    __shared__ __align__(16) float Ms[8][768];
    #pragma unroll
    for (int r = 0; r < 8; ++r)
        for (int c = tid; c < DD; c += 256)
            Ms[r][c] = hm[(size_t)(j*8 + r)*DD + c];
    __syncthreads();

    for (int nn = wave; nn < 50; nn += 4) {
        const int n = tile * 50 + nn;
        const float* qp = H + (size_t)n * JD + j * DD;
        float s = 0.f, s2 = 0.f;
#define DCL(k) float d##k = 0.f;
        FOR8(DCL)
#undef DCL
        #pragma unroll
        for (int c = 0; c < 12; ++c) {
            const int d = lane + 64 * c;
            const float qv = qp[d];
            s += qv; s2 += qv * qv;
#define MAC(k) d##k += qv * Ms[k][d];
            FOR8(MAC)
#undef MAC
        }
#define XR(v) { v += __shfl_xor(v, 32); v += __shfl_xor(v, 16); v += __shfl_xor(v, 8); \
                v += __shfl_xor(v, 4);  v += __shfl_xor(v, 2);  v += __shfl_xor(v, 1); }
#define XRD(k) XR(d##k)
        FOR8(XRD)
#undef XRD
        XR(s) XR(s2)
#undef XR
        if (lane == 0) {
#define ST(k) dmq[(size_t)n*64 + j*8 + k] = d##k;
            FOR8(ST)
#undef ST
            Sq0v[n*8 + j] = s;
            Sq20v[n*8 + j] = s2;
        }
    }
}

// ---------------- kernel 4: fused routing (3 d-space passes) ----------------
__global__ __launch_bounds__(768) void k_route2(const float* __restrict__ H,
                                                const float* __restrict__ hm,
                                                const float* __restrict__ muM,
                                                const float* __restrict__ mc2M,
                                                const float* __restrict__ G,
                                                const float* __restrict__ dmq,
                                                const float* __restrict__ Sq0v,
                                                const float* __restrict__ Sq20v,
                                                float* __restrict__ out)
{
    const int n = blockIdx.x;
    const int tid = threadIdx.x;                  // d
    const int lane = tid & 63, wave = tid >> 6;   // 12 waves
    __shared__ __align__(16) float sVv[8][768];
    __shared__ float scr[24][12];
    __shared__ float rstat[24];
    __shared__ float sDot[64];
    __shared__ float sP[64], sC1[64], sC2[64], sB1[64];

#define WRED(val, idx) { float _v = (val);                           \
    _v += __shfl_down(_v, 32); _v += __shfl_down(_v, 16);            \
    _v += __shfl_down(_v, 8);  _v += __shfl_down(_v, 4);             \
    _v += __shfl_down(_v, 2);  _v += __shfl_down(_v, 1);             \
    if (lane == 0) scr[(idx)][wave] = _v; }

#define FIN(nv) { if (tid < (nv)) { float _s = 0.f;                  \
    _Pragma("unroll")                                                \
    for (int _w = 0; _w < 12; ++_w) _s += scr[tid][_w];              \
    rstat[tid] = _s; } }

#define DOTLOOP() for (int t = wave; t < 64; t += 12) {              \
        const int _j = t >> 3;                                       \
        const float* Mrow = hm + (size_t)t * DD;                     \
        float acc = 0.f;                                             \
        _Pragma("unroll")                                            \
        for (int c = 0; c < 3; ++c) {                                \
            const int dd = c * 256 + lane * 4;                       \
            const float4 mv = *reinterpret_cast<const float4*>(Mrow + dd);       \
            const float4 vv = *reinterpret_cast<const float4*>(&sVv[_j][dd]);    \
            acc += mv.x*vv.x + mv.y*vv.y + mv.z*vv.z + mv.w*vv.w;    \
        }                                                            \
        acc += __shfl_down(acc, 32); acc += __shfl_down(acc, 16);    \
        acc += __shfl_down(acc, 8);  acc += __shfl_down(acc, 4);     \
        acc += __shfl_down(acc, 2);  acc += __shfl_down(acc, 1);     \
        if (lane == 0) sDot[t] = acc;                                \
    }

#define XR3(v) { v += __shfl_xor(v, 1); v += __shfl_xor(v, 2); v += __shfl_xor(v, 4); }

    // ---- stage 0 (wave 0): coefficient-space routing iteration 1 ----
    float w0 = 0.f, s1 = 0.f, dotM1 = 0.f, Sq1 = 0.f, Sq21 = 0.f, mu = 0.f, mc2 = 0.f;
    if (tid < 64) {
        const int j = lane >> 3;
        mu  = muM[lane];
        mc2 = mc2M[lane];
        const float smR = 768.f * mu;              // sum of M row
        const float dq  = dmq[(size_t)n * 64 + lane];
        const float Sq  = Sq0v[n * 8 + j];
        const float Sq2v = Sq20v[n * 8 + j];
        // p0 -> w0 = 1/8 + p0
        {
            float num  = dq - mu * Sq;
            float varq = fmaxf(Sq2v - Sq * Sq * (1.f / 768.f), 0.f);
            float den  = sqrtf(mc2 * varq) + EPSF;
            w0 = tanhf(num / den) + 0.125f;
        }
        // Gw0
        const float* Gr = G + lane * 8;
        const int base = lane & ~7;
        float gw = 0.f;
        #pragma unroll
        for (int ii = 0; ii < 8; ++ii) gw += Gr[ii] * __shfl(w0, base + ii);
        float n2h1 = w0 * gw;  XR3(n2h1);          // |hv1|^2
        float dqh1 = w0 * dq;  XR3(dqh1);          // dot(q', hv1)
        float Sh1  = w0 * smR; XR3(Sh1);           // sum(hv1)
        s1 = n2h1 / ((1.f + n2h1) * sqrtf(n2h1 + EPSF));
        float c1 = s1 * gw;
        sC1[lane] = c1;
        sB1[lane] = 0.5f * s1 * w0;
        dotM1 = 0.5f * (dq + c1);
        Sq1   = 0.5f * (Sq + s1 * Sh1);
        Sq21  = 0.25f * (Sq2v + 2.f * s1 * dqh1 + s1 * s1 * n2h1);   // |tq1|^2
        float varq1 = fmaxf(Sq21 - Sq1 * Sq1 * (1.f / 768.f), 0.f);
        sP[lane] = tanhf((dotM1 - mu * Sq1) / (sqrtf(mc2 * varq1) + EPSF));  // p1
    }
    __syncthreads();

    // ---- pass 1 (d-space): hv2 + tq1 reconstruction ----
    const float* Hn = H + (size_t)n * JD + tid;
    const float* hmp = hm + tid;
#define DECL(k) float t0_##k = Hn[k * DD]; float tq1_##k = 0.5f * t0_##k; float vh_##k = 0.f;
    FOR8(DECL)
#undef DECL
    #pragma unroll
    for (int i = 0; i < 8; ++i) {
#define XA(k) float x##k = t0_##k * sC1[k * 8 + i];
        FOR8(XA)
#undef XA
        float mx = fmaxf(fmaxf(fmaxf(x0, x1), fmaxf(x2, x3)),
                         fmaxf(fmaxf(x4, x5), fmaxf(x6, x7)));
#define XE(k) x##k = expf(x##k - mx);
        FOR8(XE)
#undef XE
        float inv = 1.f / (x0 + x1 + x2 + x3 + x4 + x5 + x6 + x7);
#define XACC(k) { float mval = hmp[(size_t)(k * 8 + i) * DD];        \
        vh_##k  += (x##k * inv + sP[k * 8 + i]) * mval;              \
        tq1_##k += sB1[k * 8 + i] * mval; }
        FOR8(XACC)
#undef XACC
    }
#define STG(k) sVv[k][tid] = vh_##k;                                 \
    WRED(vh_##k * vh_##k, k); WRED(vh_##k, 8 + k); WRED(t0_##k * vh_##k, 16 + k);
    FOR8(STG)
#undef STG
    __syncthreads();
    // ---- pass 2: u[ji] = M_ji . hv2_j ----
    DOTLOOP();
    FIN(24);
    __syncthreads();

    // ---- stage 2 (wave 0): p2, c2 ----
    if (tid < 64) {
        const int j = lane >> 3;
        const float n2h2 = rstat[j];               // |hv2|^2
        const float Sh2  = rstat[8 + j];           // sum(hv2)
        const float dqh2 = rstat[16 + j];          // dot(q', hv2)
        const float u = sDot[lane];                // dot(M_ji, hv2_j)
        float s2 = n2h2 / ((1.f + n2h2) * sqrtf(n2h2 + EPSF));
        float c2 = s2 * u;
        sC2[lane] = c2;
        float dotM2 = 0.5f * (dotM1 + c2);
        float w0u = w0 * u; XR3(w0u);              // dot(hv1, hv2)
        float dt1h2 = 0.5f * (dqh2 + s1 * w0u);    // dot(tq1, hv2)
        float Sq2_ = 0.5f * (Sq1 + s2 * Sh2);
        float Sq22 = 0.25f * Sq21 + 0.5f * s2 * dt1h2 + 0.25f * s2 * s2 * n2h2;  // |tq2|^2
        float varq2 = fmaxf(Sq22 - Sq2_ * Sq2_ * (1.f / 768.f), 0.f);
        sP[lane] = tanhf((dotM2 - mu * Sq2_) / (sqrtf(mc2 * varq2) + EPSF));     // p2
    }
    __syncthreads();

    // ---- pass 3 (d-space): final softmax + hv3 + squash + write ----
#define ZV(k) vh_##k = 0.f;
    FOR8(ZV)
#undef ZV
    #pragma unroll
    for (int i = 0; i < 8; ++i) {
#define XA(k) float x##k = t0_##k * sC1[k * 8 + i] + tq1_##k * sC2[k * 8 + i];
        FOR8(XA)
#undef XA
        float mx = fmaxf(fmaxf(fmaxf(x0, x1), fmaxf(x2, x3)),
                         fmaxf(fmaxf(x4, x5), fmaxf(x6, x7)));
#define XE(k) x##k = expf(x##k - mx);
        FOR8(XE)
#undef XE
        float inv = 1.f / (x0 + x1 + x2 + x3 + x4 + x5 + x6 + x7);
#define XACC(k) vh_##k += (x##k * inv + sP[k * 8 + i]) * hmp[(size_t)(k * 8 + i) * DD];
        FOR8(XACC)
#undef XACC
    }
#define NRM(k) WRED(vh_##k * vh_##k, k);
    FOR8(NRM)
#undef NRM
    __syncthreads();
    FIN(8);
    __syncthreads();
    float* On = out + (size_t)n * JD + tid;
#define WOUT(k) { float n2 = rstat[k];                               \
        float sc = n2 / ((1.f + n2) * sqrtf(n2 + EPSF));             \
        On[k * DD] = vh_##k * sc; }
    FOR8(WOUT)
#undef WOUT
#undef WRED
#undef FIN
#undef DOTLOOP
#undef XR3
}

extern "C" void kernel_launch(void* const* d_in, const int* in_sizes, int n_in,
                              void* d_out, int out_size, void* d_ws, size_t ws_size,
                              hipStream_t stream) {
    const float* m  = (const float*)d_in[0];   // [8,768]
    const float* q  = (const float*)d_in[1];   // [400,768]
    const float* W  = (const float*)d_in[2];   // [1,8,8,768,768]
    const float* b  = (const float*)d_in[3];   // [1,8,8,768]
    const float* Wn = (const float*)d_in[4];   // [768,768]
    float* out = (float*)d_out;
    float* ws  = (float*)d_ws;

    float* mproj = ws + OFF_MPROJ;
    float* H     = ws + OFF_H;
    float* hm    = ws + OFF_HM;
    float* muM   = ws + OFF_MU;
    float* mc2M  = ws + OFF_MC2;
    float* G     = ws + OFF_G;
    float* dmq   = ws + OFF_DMQ;
    float* Sq0v  = ws + OFF_SQ0;
    float* Sq20v = ws + OFF_SQ20;

    k_mproj<<<dim3(3, 8), 256, 0, stream>>>(m, Wn, mproj);
    k_gemm<<<dim3(96, 7), 256, 0, stream>>>(q, mproj, W, H);
    k_prep<<<dim3(64), 256, 0, stream>>>(H, b, hm, muM, mc2M);
    k_gram<<<dim3(64), 256, 0, stream>>>(hm, G);
    k_dots<<<dim3(8, 8), 256, 0, stream>>>(H, hm, dmq, Sq0v, Sq20v);
    k_route2<<<dim3(400), 768, 0, stream>>>(H, hm, muM, mc2M, G, dmq, Sq0v, Sq20v, out);
}

// Round 5
// 212.772 us; speedup vs baseline: 3.5340x; 1.4393x over previous
//
#include <hip/hip_runtime.h>
#include <math.h>

#define DD    768
#define NQ    400
#define NROWS 408          // 400 q rows + 8 m_proj rows
#define JD    6144         // J*D = 8*768
#define WSLICE 4718592     // I*D*E = 8*768*768 (stride between j slices of W)
#define EPSF  1e-8f

// ---------------- workspace layout (floats) ----------------
#define OFF_MPROJ 0                       // [8][768]
#define OFF_H     6144                    // [408][6144]
#define OFF_HM    (OFF_H + 408*6144)      // [64][768]  (j*8+i major)
#define OFF_MU    (OFF_HM + 64*768)       // [64]
#define OFF_MC2   (OFF_MU + 64)           // [64]
#define OFF_G     (OFF_MC2 + 64)          // [64][8]  Gram
#define OFF_DMQ   (OFF_G + 512)           // [400][64] dot(M_ji, q'_nj)
#define OFF_SQ0   (OFF_DMQ + 400*64)      // [400][8]  sum(q'_nj)
#define OFF_SQ20  (OFF_SQ0 + 400*8)       // [400][8]  sumsq(q'_nj)

#define FOR8(M) M(0) M(1) M(2) M(3) M(4) M(5) M(6) M(7)

// ---------------- kernel 1: m_proj = m @ W_n ----------------
__global__ __launch_bounds__(256) void k_mproj(const float* __restrict__ m,
                                               const float* __restrict__ Wn,
                                               float* __restrict__ mproj)
{
    const int i = blockIdx.y;
    const int d = blockIdx.x * 256 + threadIdx.x;
    float acc = 0.f;
    #pragma unroll 8
    for (int e = 0; e < DD; ++e)
        acc += m[i*DD + e] * Wn[(size_t)e*DD + d];
    mproj[i*DD + d] = acc;
}

// ---------------- kernel 2: H[x, j*768+d] = sum_e W[j,0,d,e] * X[x,e] ----------------
__global__ __launch_bounds__(256) void k_gemm(const float* __restrict__ q,
                                              const float* __restrict__ mproj,
                                              const float* __restrict__ W,
                                              float* __restrict__ H)
{
    __shared__ float As[32][68];
    __shared__ float Bs[32][68];
    const int tid = threadIdx.x;
    const int tx = tid & 15;
    const int ty = tid >> 4;
    const int c0 = blockIdx.x * 64;
    const int m0 = blockIdx.y * 64;
    const int j  = c0 / DD;
    const int d0 = c0 % DD;
    const float* Bbase = W + (size_t)j * WSLICE + (size_t)d0 * DD;
    const int lrow = tid >> 3;
    const int lk   = (tid & 7) << 2;
    float acc[4][4] = {};

    for (int k0 = 0; k0 < DD; k0 += 32) {
        #pragma unroll
        for (int h = 0; h < 2; ++h) {
            const int r  = lrow + h * 32;
            const int gr = m0 + r;
            float4 av = make_float4(0.f, 0.f, 0.f, 0.f);
            if (gr < NROWS) {
                const float* Arow = (gr < NQ) ? (q + (size_t)gr * DD)
                                              : (mproj + (size_t)(gr - NQ) * DD);
                av = *reinterpret_cast<const float4*>(Arow + k0 + lk);
            }
            As[lk+0][r] = av.x; As[lk+1][r] = av.y; As[lk+2][r] = av.z; As[lk+3][r] = av.w;
            const float4 bv = *reinterpret_cast<const float4*>(Bbase + (size_t)r * DD + k0 + lk);
            Bs[lk+0][r] = bv.x; Bs[lk+1][r] = bv.y; Bs[lk+2][r] = bv.z; Bs[lk+3][r] = bv.w;
        }
        __syncthreads();
        #pragma unroll
        for (int k = 0; k < 32; ++k) {
            const float4 a4 = *reinterpret_cast<const float4*>(&As[k][ty * 4]);
            const float4 b4 = *reinterpret_cast<const float4*>(&Bs[k][tx * 4]);
            acc[0][0] += a4.x * b4.x; acc[0][1] += a4.x * b4.y; acc[0][2] += a4.x * b4.z; acc[0][3] += a4.x * b4.w;
            acc[1][0] += a4.y * b4.x; acc[1][1] += a4.y * b4.y; acc[1][2] += a4.y * b4.z; acc[1][3] += a4.y * b4.w;
            acc[2][0] += a4.z * b4.x; acc[2][1] += a4.z * b4.y; acc[2][2] += a4.z * b4.z; acc[2][3] += a4.z * b4.w;
            acc[3][0] += a4.w * b4.x; acc[3][1] += a4.w * b4.y; acc[3][2] += a4.w * b4.z; acc[3][3] += a4.w * b4.w;
        }
        __syncthreads();
    }
    #pragma unroll
    for (int r = 0; r < 4; ++r) {
        const int gr = m0 + ty * 4 + r;
        if (gr < NROWS) {
            float4 o = make_float4(acc[r][0], acc[r][1], acc[r][2], acc[r][3]);
            *reinterpret_cast<float4*>(H + (size_t)gr * JD + c0 + tx * 4) = o;
        }
    }
}

// ---------------- kernel 3: hat_m + Pearson stats of M rows ----------------
__global__ __launch_bounds__(256) void k_prep(const float* __restrict__ H,
                                              const float* __restrict__ b,
                                              float* __restrict__ hm,
                                              float* __restrict__ muM,
                                              float* __restrict__ mc2M)
{
    const int ji = blockIdx.x;
    const int j = ji >> 3, i = ji & 7;
    const int tid = threadIdx.x;
    const int lane = tid & 63, wave = tid >> 6;
    __shared__ float scr[4];
    __shared__ float smu;
    float vals[3];
    float s = 0.f;
    #pragma unroll
    for (int u = 0; u < 3; ++u) {
        const int d = u * 256 + tid;
        float x = H[(size_t)(NQ + i) * JD + j * DD + d] + b[(size_t)ji * DD + d];
        hm[(size_t)ji * DD + d] = x;
        vals[u] = x;
        s += x;
    }
    #pragma unroll
    for (int off = 32; off; off >>= 1) s += __shfl_down(s, off);
    if (lane == 0) scr[wave] = s;
    __syncthreads();
    if (tid == 0) smu = (scr[0] + scr[1] + scr[2] + scr[3]) * (1.f / 768.f);
    __syncthreads();
    const float mu = smu;
    float s2 = 0.f;
    #pragma unroll
    for (int u = 0; u < 3; ++u) { float c = vals[u] - mu; s2 += c * c; }
    __syncthreads();
    #pragma unroll
    for (int off = 32; off; off >>= 1) s2 += __shfl_down(s2, off);
    if (lane == 0) scr[wave] = s2;
    __syncthreads();
    if (tid == 0) { muM[ji] = mu; mc2M[ji] = scr[0] + scr[1] + scr[2] + scr[3]; }
}

// ---------------- kernel 3b: Gram matrix G[ji][i'] = M_ji . M_ji' ----------------
__global__ __launch_bounds__(256) void k_gram(const float* __restrict__ hm,
                                              float* __restrict__ G)
{
    const int ji = blockIdx.x;          // 0..63
    const int j = ji >> 3;
    const int tid = threadIdx.x;
    const int lane = tid & 63, wave = tid >> 6;
    __shared__ float scr[8][4];
    const float a0 = hm[(size_t)ji*DD + tid];
    const float a1 = hm[(size_t)ji*DD + 256 + tid];
    const float a2 = hm[(size_t)ji*DD + 512 + tid];
#define GDOT(k) { const float* Bp = hm + (size_t)(j*8 + k)*DD + tid;             \
        float acc = a0*Bp[0] + a1*Bp[256] + a2*Bp[512];                          \
        acc += __shfl_down(acc, 32); acc += __shfl_down(acc, 16);                \
        acc += __shfl_down(acc, 8);  acc += __shfl_down(acc, 4);                 \
        acc += __shfl_down(acc, 2);  acc += __shfl_down(acc, 1);                 \
        if (lane == 0) scr[k][wave] = acc; }
    FOR8(GDOT)
#undef GDOT
    __syncthreads();
    if (tid < 8) G[ji*8 + tid] = scr[tid][0] + scr[tid][1] + scr[tid][2] + scr[tid][3];
}

// ---------------- kernel 3c: per-n dots dmq[n][ji] = M_ji . q'_nj + q' stats ----
__global__ __launch_bounds__(256) void k_dots(const float* __restrict__ H,
                                              const float* __restrict__ hm,
                                              float* __restrict__ dmq,
                                              float* __restrict__ Sq0v,
                                              float* __restrict__ Sq20v)
{
    const int j = blockIdx.x;           // 0..7
    const int tile = blockIdx.y;        // 0..7 (50 n each)
    const int tid = threadIdx.x;
    const int lane = tid & 63, wave = tid >> 6;   // 4 waves
    __shared__ __align__(16) float Ms[8][768];
    #pragma unroll
    for (int r = 0; r < 8; ++r)
        for (int c = tid; c < DD; c += 256)
            Ms[r][c] = hm[(size_t)(j*8 + r)*DD + c];
    __syncthreads();

    for (int nn = wave; nn < 50; nn += 4) {
        const int n = tile * 50 + nn;
        const float* qp = H + (size_t)n * JD + j * DD;
        float s = 0.f, s2 = 0.f;
#define DCL(k) float d##k = 0.f;
        FOR8(DCL)
#undef DCL
        #pragma unroll 2
        for (int c = 0; c < 12; ++c) {
            const int d = lane + 64 * c;
            const float qv = qp[d];
            s += qv; s2 += qv * qv;
#define MAC(k) d##k += qv * Ms[k][d];
            FOR8(MAC)
#undef MAC
        }
#define XR(v) { v += __shfl_xor(v, 32); v += __shfl_xor(v, 16); v += __shfl_xor(v, 8); \
                v += __shfl_xor(v, 4);  v += __shfl_xor(v, 2);  v += __shfl_xor(v, 1); }
#define XRD(k) XR(d##k)
        FOR8(XRD)
#undef XRD
        XR(s) XR(s2)
#undef XR
        if (lane == 0) {
#define ST(k) dmq[(size_t)n*64 + j*8 + k] = d##k;
            FOR8(ST)
#undef ST
            Sq0v[n*8 + j] = s;
            Sq20v[n*8 + j] = s2;
        }
    }
}

// ---------------- kernel 4: fused routing (3 d-space passes) ----------------
__global__ __launch_bounds__(768) void k_route2(const float* __restrict__ H,
                                                const float* __restrict__ hm,
                                                const float* __restrict__ muM,
                                                const float* __restrict__ mc2M,
                                                const float* __restrict__ G,
                                                const float* __restrict__ dmq,
                                                const float* __restrict__ Sq0v,
                                                const float* __restrict__ Sq20v,
                                                float* __restrict__ out)
{
    const int n = blockIdx.x;
    const int tid = threadIdx.x;                  // d
    const int lane = tid & 63, wave = tid >> 6;   // 12 waves
    __shared__ __align__(16) float sVv[8][768];
    __shared__ float scr[24][12];
    __shared__ float rstat[24];
    __shared__ float sDot[64];
    __shared__ float sP[64], sC1[64], sC2[64], sB1[64];

#define WRED(val, idx) { float _v = (val);                           \
    _v += __shfl_down(_v, 32); _v += __shfl_down(_v, 16);            \
    _v += __shfl_down(_v, 8);  _v += __shfl_down(_v, 4);             \
    _v += __shfl_down(_v, 2);  _v += __shfl_down(_v, 1);             \
    if (lane == 0) scr[(idx)][wave] = _v; }

#define FIN(nv) { if (tid < (nv)) { float _s = 0.f;                  \
    _Pragma("unroll")                                                \
    for (int _w = 0; _w < 12; ++_w) _s += scr[tid][_w];              \
    rstat[tid] = _s; } }

#define DOTLOOP() for (int t = wave; t < 64; t += 12) {              \
        const int _j = t >> 3;                                       \
        const float* Mrow = hm + (size_t)t * DD;                     \
        float acc = 0.f;                                             \
        _Pragma("unroll")                                            \
        for (int c = 0; c < 3; ++c) {                                \
            const int dd = c * 256 + lane * 4;                       \
            const float4 mv = *reinterpret_cast<const float4*>(Mrow + dd);       \
            const float4 vv = *reinterpret_cast<const float4*>(&sVv[_j][dd]);    \
            acc += mv.x*vv.x + mv.y*vv.y + mv.z*vv.z + mv.w*vv.w;    \
        }                                                            \
        acc += __shfl_down(acc, 32); acc += __shfl_down(acc, 16);    \
        acc += __shfl_down(acc, 8);  acc += __shfl_down(acc, 4);     \
        acc += __shfl_down(acc, 2);  acc += __shfl_down(acc, 1);     \
        if (lane == 0) sDot[t] = acc;                                \
    }

#define XR3(v) { v += __shfl_xor(v, 1); v += __shfl_xor(v, 2); v += __shfl_xor(v, 4); }

    // ---- stage 0 (wave 0): coefficient-space routing iteration 1 ----
    float w0 = 0.f, s1 = 0.f, dotM1 = 0.f, Sq1 = 0.f, Sq21 = 0.f, mu = 0.f, mc2 = 0.f;
    if (tid < 64) {
        const int j = lane >> 3;
        mu  = muM[lane];
        mc2 = mc2M[lane];
        const float smR = 768.f * mu;              // sum of M row
        const float dq  = dmq[(size_t)n * 64 + lane];
        const float Sq  = Sq0v[n * 8 + j];
        const float Sq2v = Sq20v[n * 8 + j];
        // p0 -> w0 = 1/8 + p0
        {
            float num  = dq - mu * Sq;
            float varq = fmaxf(Sq2v - Sq * Sq * (1.f / 768.f), 0.f);
            float den  = sqrtf(mc2 * varq) + EPSF;
            w0 = tanhf(num / den) + 0.125f;
        }
        // Gw0
        const float* Gr = G + lane * 8;
        const int base = lane & ~7;
        float gw = 0.f;
        #pragma unroll
        for (int ii = 0; ii < 8; ++ii) gw += Gr[ii] * __shfl(w0, base + ii);
        float n2h1 = w0 * gw;  XR3(n2h1);          // |hv1|^2
        float dqh1 = w0 * dq;  XR3(dqh1);          // dot(q', hv1)
        float Sh1  = w0 * smR; XR3(Sh1);           // sum(hv1)
        s1 = n2h1 / ((1.f + n2h1) * sqrtf(n2h1 + EPSF));
        float c1 = s1 * gw;
        sC1[lane] = c1;
        sB1[lane] = 0.5f * s1 * w0;
        dotM1 = 0.5f * (dq + c1);
        Sq1   = 0.5f * (Sq + s1 * Sh1);
        Sq21  = 0.25f * (Sq2v + 2.f * s1 * dqh1 + s1 * s1 * n2h1);   // |tq1|^2
        float varq1 = fmaxf(Sq21 - Sq1 * Sq1 * (1.f / 768.f), 0.f);
        sP[lane] = tanhf((dotM1 - mu * Sq1) / (sqrtf(mc2 * varq1) + EPSF));  // p1
    }
    __syncthreads();

    // ---- pass 1 (d-space): hv2 + tq1 reconstruction ----
    const float* Hn = H + (size_t)n * JD + tid;
    const float* hmp = hm + tid;
#define DECL(k) float t0_##k = Hn[k * DD]; float tq1_##k = 0.5f * t0_##k; float vh_##k = 0.f;
    FOR8(DECL)
#undef DECL
    #pragma unroll 1
    for (int i = 0; i < 8; ++i) {
#define XA(k) float x##k = t0_##k * sC1[k * 8 + i];
        FOR8(XA)
#undef XA
        float mx = fmaxf(fmaxf(fmaxf(x0, x1), fmaxf(x2, x3)),
                         fmaxf(fmaxf(x4, x5), fmaxf(x6, x7)));
#define XE(k) x##k = expf(x##k - mx);
        FOR8(XE)
#undef XE
        float inv = 1.f / (x0 + x1 + x2 + x3 + x4 + x5 + x6 + x7);
#define XACC(k) { float mval = hmp[(size_t)(k * 8 + i) * DD];        \
        vh_##k  += (x##k * inv + sP[k * 8 + i]) * mval;              \
        tq1_##k += sB1[k * 8 + i] * mval; }
        FOR8(XACC)
#undef XACC
    }
#define STG(k) sVv[k][tid] = vh_##k;                                 \
    WRED(vh_##k * vh_##k, k); WRED(vh_##k, 8 + k); WRED(t0_##k * vh_##k, 16 + k);
    FOR8(STG)
#undef STG
    __syncthreads();
    // ---- pass 2: u[ji] = M_ji . hv2_j ----
    DOTLOOP();
    FIN(24);
    __syncthreads();

    // ---- stage 2 (wave 0): p2, c2 ----
    if (tid < 64) {
        const int j = lane >> 3;
        const float n2h2 = rstat[j];               // |hv2|^2
        const float Sh2  = rstat[8 + j];           // sum(hv2)
        const float dqh2 = rstat[16 + j];          // dot(q', hv2)
        const float u = sDot[lane];                // dot(M_ji, hv2_j)
        float s2 = n2h2 / ((1.f + n2h2) * sqrtf(n2h2 + EPSF));
        float c2 = s2 * u;
        sC2[lane] = c2;
        float dotM2 = 0.5f * (dotM1 + c2);
        float w0u = w0 * u; XR3(w0u);              // dot(hv1, hv2)
        float dt1h2 = 0.5f * (dqh2 + s1 * w0u);    // dot(tq1, hv2)
        float Sq2_ = 0.5f * (Sq1 + s2 * Sh2);
        float Sq22 = 0.25f * Sq21 + 0.5f * s2 * dt1h2 + 0.25f * s2 * s2 * n2h2;  // |tq2|^2
        float varq2 = fmaxf(Sq22 - Sq2_ * Sq2_ * (1.f / 768.f), 0.f);
        sP[lane] = tanhf((dotM2 - mu * Sq2_) / (sqrtf(mc2 * varq2) + EPSF));     // p2
    }
    __syncthreads();

    // ---- pass 3 (d-space): final softmax + hv3 + squash + write ----
#define ZV(k) vh_##k = 0.f;
    FOR8(ZV)
#undef ZV
    #pragma unroll 1
    for (int i = 0; i < 8; ++i) {
#define XA(k) float x##k = t0_##k * sC1[k * 8 + i] + tq1_##k * sC2[k * 8 + i];
        FOR8(XA)
#undef XA
        float mx = fmaxf(fmaxf(fmaxf(x0, x1), fmaxf(x2, x3)),
                         fmaxf(fmaxf(x4, x5), fmaxf(x6, x7)));
#define XE(k) x##k = expf(x##k - mx);
        FOR8(XE)
#undef XE
        float inv = 1.f / (x0 + x1 + x2 + x3 + x4 + x5 + x6 + x7);
#define XACC(k) vh_##k += (x##k * inv + sP[k * 8 + i]) * hmp[(size_t)(k * 8 + i) * DD];
        FOR8(XACC)
#undef XACC
    }
#define NRM(k) WRED(vh_##k * vh_##k, k);
    FOR8(NRM)
#undef NRM
    __syncthreads();
    FIN(8);
    __syncthreads();
    float* On = out + (size_t)n * JD + tid;
#define WOUT(k) { float n2 = rstat[k];                               \
        float sc = n2 / ((1.f + n2) * sqrtf(n2 + EPSF));             \
        On[k * DD] = vh_##k * sc; }
    FOR8(WOUT)
#undef WOUT
#undef WRED
#undef FIN
#undef DOTLOOP
#undef XR3
}

extern "C" void kernel_launch(void* const* d_in, const int* in_sizes, int n_in,
                              void* d_out, int out_size, void* d_ws, size_t ws_size,
                              hipStream_t stream) {
    const float* m  = (const float*)d_in[0];   // [8,768]
    const float* q  = (const float*)d_in[1];   // [400,768]
    const float* W  = (const float*)d_in[2];   // [1,8,8,768,768]
    const float* b  = (const float*)d_in[3];   // [1,8,8,768]
    const float* Wn = (const float*)d_in[4];   // [768,768]
    float* out = (float*)d_out;
    float* ws  = (float*)d_ws;

    float* mproj = ws + OFF_MPROJ;
    float* H     = ws + OFF_H;
    float* hm    = ws + OFF_HM;
    float* muM   = ws + OFF_MU;
    float* mc2M  = ws + OFF_MC2;
    float* G     = ws + OFF_G;
    float* dmq   = ws + OFF_DMQ;
    float* Sq0v  = ws + OFF_SQ0;
    float* Sq20v = ws + OFF_SQ20;

    k_mproj<<<dim3(3, 8), 256, 0, stream>>>(m, Wn, mproj);
    k_gemm<<<dim3(96, 7), 256, 0, stream>>>(q, mproj, W, H);
    k_prep<<<dim3(64), 256, 0, stream>>>(H, b, hm, muM, mc2M);
    k_gram<<<dim3(64), 256, 0, stream>>>(hm, G);
    k_dots<<<dim3(8, 8), 256, 0, stream>>>(H, hm, dmq, Sq0v, Sq20v);
    k_route2<<<dim3(400), 768, 0, stream>>>(H, hm, muM, mc2M, G, dmq, Sq0v, Sq20v, out);
}

// Round 6
// 200.828 us; speedup vs baseline: 3.7442x; 1.0595x over previous
//
#include <hip/hip_runtime.h>
#include <math.h>

#define DD    768
#define NQ    400
#define NROWS 408          // 400 q rows + 8 m_proj rows
#define JD    6144         // J*D = 8*768
#define WSLICE 4718592     // I*D*E = 8*768*768 (stride between j slices of W)
#define EPSF  1e-8f
#define K2    2304         // split-bf16 packed K (3 segments of 768)

// ---------------- workspace layout (floats) ----------------
#define OFF_MPROJ 0                       // [8][768]
#define OFF_H     6144                    // [408][6144]
#define OFF_HM    (OFF_H + 408*6144)      // [64][768]  (j*8+i major)
#define OFF_MU    (OFF_HM + 64*768)       // [64]
#define OFF_MC2   (OFF_MU + 64)           // [64]
#define OFF_G     (OFF_MC2 + 64)          // [64][8]  Gram
#define OFF_DMQ   (OFF_G + 512)           // [400][64] dot(M_ji, q'_nj)
#define OFF_SQ0   (OFF_DMQ + 400*64)      // [400][8]  sum(q'_nj)
#define OFF_SQ20  (OFF_SQ0 + 400*8)       // [400][8]  sumsq(q'_nj)
#define OFF_A2    (OFF_SQ20 + 400*8)      // [512][2304] bf16 (as u16; 589824 floats)
#define OFF_B2    (OFF_A2 + 512*K2/2)     // [6144][2304] bf16 (7077888 floats)

#define FOR8(M) M(0) M(1) M(2) M(3) M(4) M(5) M(6) M(7)

typedef __attribute__((ext_vector_type(8))) short short8v;
typedef __attribute__((ext_vector_type(4))) float float4v;

__device__ inline unsigned short f2bf(float x) {
    unsigned u = __float_as_uint(x);
    u += 0x7FFF + ((u >> 16) & 1);
    return (unsigned short)(u >> 16);
}
__device__ inline float bf2f(unsigned short h) {
    return __uint_as_float(((unsigned)h) << 16);
}

// ---------------- kernel 1: m_proj = m @ W_n ----------------
__global__ __launch_bounds__(256) void k_mproj(const float* __restrict__ m,
                                               const float* __restrict__ Wn,
                                               float* __restrict__ mproj)
{
    const int i = blockIdx.y;
    const int d = blockIdx.x * 256 + threadIdx.x;
    float acc = 0.f;
    #pragma unroll 8
    for (int e = 0; e < DD; ++e)
        acc += m[i*DD + e] * Wn[(size_t)e*DD + d];
    mproj[i*DD + d] = acc;
}

// ---------------- kernel 1b: pack A'' = [hi | lo | hi] (rows: q then mproj) ----
__global__ __launch_bounds__(256) void k_cvtA(const float* __restrict__ q,
                                              const float* __restrict__ mproj,
                                              unsigned short* __restrict__ A2)
{
    const int r = blockIdx.x;          // 0..407
    const float* src = (r < NQ) ? (q + (size_t)r * DD) : (mproj + (size_t)(r - NQ) * DD);
    unsigned short* dst = A2 + (size_t)r * K2;
    for (int u = threadIdx.x; u < DD; u += 256) {
        float x = src[u];
        unsigned short hi = f2bf(x);
        unsigned short lo = f2bf(x - bf2f(hi));
        dst[u] = hi; dst[DD + u] = lo; dst[2*DD + u] = hi;
    }
}

// ---------------- kernel 1c: pack B'' = [hi | hi | lo] from W[j,0,d,:] --------
__global__ __launch_bounds__(256) void k_cvtB(const float* __restrict__ W,
                                              unsigned short* __restrict__ B2)
{
    const int rw = blockIdx.x;         // 0..6143 = j*768 + d
    const int j = rw >> 9 ; // rw / 512? NO
    // careful: 768 per j -> j = rw / 768
    const int jj = rw / 768;
    const int d  = rw - jj * 768;
    const float* src = W + (size_t)jj * WSLICE + (size_t)d * DD;
    unsigned short* dst = B2 + (size_t)rw * K2;
    (void)j;
    for (int u = threadIdx.x; u < DD; u += 256) {
        float x = src[u];
        unsigned short hi = f2bf(x);
        unsigned short lo = f2bf(x - bf2f(hi));
        dst[u] = hi; dst[DD + u] = hi; dst[2*DD + u] = lo;
    }
}

// ---------------- kernel 2: MFMA GEMM  H[r, c] = sum_k A''[r,k]*B''[c,k] ------
// 128x128 tile, BK=64, 4 waves (2x2), 16x16x32 bf16 MFMA, global_load_lds w16,
// XOR-swizzled LDS (pre-swizzled global source + swizzled ds_read).
__global__ __launch_bounds__(256) void k_gemm_mfma(const unsigned short* __restrict__ A2,
                                                   const unsigned short* __restrict__ B2,
                                                   float* __restrict__ H)
{
    __shared__ __align__(16) unsigned short lds[16384];   // A:[0,8192) B:[8192,16384)
    const int tid = threadIdx.x;
    const int wv  = tid >> 6;
    const int ln  = tid & 63;
    const int c0  = blockIdx.x * 128;
    const int m0  = blockIdx.y * 128;
    const int wm  = (wv >> 1) * 64;
    const int wn  = (wv & 1) * 64;
    const unsigned short* Ap = A2 + (size_t)m0 * K2;
    const unsigned short* Bp = B2 + (size_t)c0 * K2;

    float4v acc[4][4];
    #pragma unroll
    for (int a = 0; a < 4; ++a)
        #pragma unroll
        for (int b = 0; b < 4; ++b)
            acc[a][b] = (float4v){0.f, 0.f, 0.f, 0.f};

    for (int k0 = 0; k0 < K2; k0 += 64) {
        #pragma unroll
        for (int qq = 0; qq < 4; ++qq) {
            const int idx = (qq << 8) + tid;          // 0..1023
            const int row = idx >> 3;                 // 0..127
            const int ce  = ((idx & 7) ^ (row & 7)) << 3;   // source col (elems), pre-swizzled
            __builtin_amdgcn_global_load_lds(
                (const __attribute__((address_space(1))) void*)(Ap + (size_t)row * K2 + k0 + ce),
                (__attribute__((address_space(3))) void*)(lds + idx * 8), 16, 0, 0);
            __builtin_amdgcn_global_load_lds(
                (const __attribute__((address_space(1))) void*)(Bp + (size_t)row * K2 + k0 + ce),
                (__attribute__((address_space(3))) void*)(lds + 8192 + idx * 8), 16, 0, 0);
        }
        __syncthreads();
        #pragma unroll
        for (int s = 0; s < 2; ++s) {
            short8v af[4], bf[4];
            #pragma unroll
            for (int mi = 0; mi < 4; ++mi) {
                const int row = wm + mi * 16 + (ln & 15);
                const int off = row * 64 + ((s * 32 + ((ln >> 4) * 8)) ^ ((row & 7) << 3));
                af[mi] = *reinterpret_cast<const short8v*>(lds + off);
            }
            #pragma unroll
            for (int ni = 0; ni < 4; ++ni) {
                const int row = wn + ni * 16 + (ln & 15);
                const int off = row * 64 + ((s * 32 + ((ln >> 4) * 8)) ^ ((row & 7) << 3));
                bf[ni] = *reinterpret_cast<const short8v*>(lds + 8192 + off);
            }
            #pragma unroll
            for (int mi = 0; mi < 4; ++mi)
                #pragma unroll
                for (int ni = 0; ni < 4; ++ni)
                    acc[mi][ni] = __builtin_amdgcn_mfma_f32_16x16x32_bf16(af[mi], bf[ni], acc[mi][ni], 0, 0, 0);
        }
        __syncthreads();
    }
    // epilogue: C[row = (ln>>4)*4 + r, col = ln&15] per 16x16 fragment
    #pragma unroll
    for (int mi = 0; mi < 4; ++mi) {
        #pragma unroll
        for (int r = 0; r < 4; ++r) {
            const int gr = m0 + wm + mi * 16 + (ln >> 4) * 4 + r;
            if (gr < NROWS) {
                #pragma unroll
                for (int ni = 0; ni < 4; ++ni)
                    H[(size_t)gr * JD + c0 + wn + ni * 16 + (ln & 15)] = acc[mi][ni][r];
            }
        }
    }
}

// ---------------- kernel 3: hat_m + Pearson stats of M rows ----------------
__global__ __launch_bounds__(256) void k_prep(const float* __restrict__ H,
                                              const float* __restrict__ b,
                                              float* __restrict__ hm,
                                              float* __restrict__ muM,
                                              float* __restrict__ mc2M)
{
    const int ji = blockIdx.x;
    const int j = ji >> 3, i = ji & 7;
    const int tid = threadIdx.x;
    const int lane = tid & 63, wave = tid >> 6;
    __shared__ float scr[4];
    __shared__ float smu;
    float vals[3];
    float s = 0.f;
    #pragma unroll
    for (int u = 0; u < 3; ++u) {
        const int d = u * 256 + tid;
        float x = H[(size_t)(NQ + i) * JD + j * DD + d] + b[(size_t)ji * DD + d];
        hm[(size_t)ji * DD + d] = x;
        vals[u] = x;
        s += x;
    }
    #pragma unroll
    for (int off = 32; off; off >>= 1) s += __shfl_down(s, off);
    if (lane == 0) scr[wave] = s;
    __syncthreads();
    if (tid == 0) smu = (scr[0] + scr[1] + scr[2] + scr[3]) * (1.f / 768.f);
    __syncthreads();
    const float mu = smu;
    float s2 = 0.f;
    #pragma unroll
    for (int u = 0; u < 3; ++u) { float c = vals[u] - mu; s2 += c * c; }
    __syncthreads();
    #pragma unroll
    for (int off = 32; off; off >>= 1) s2 += __shfl_down(s2, off);
    if (lane == 0) scr[wave] = s2;
    __syncthreads();
    if (tid == 0) { muM[ji] = mu; mc2M[ji] = scr[0] + scr[1] + scr[2] + scr[3]; }
}

// ---------------- kernel 3b: Gram matrix G[ji][i'] = M_ji . M_ji' ----------------
__global__ __launch_bounds__(256) void k_gram(const float* __restrict__ hm,
                                              float* __restrict__ G)
{
    const int ji = blockIdx.x;          // 0..63
    const int j = ji >> 3;
    const int tid = threadIdx.x;
    const int lane = tid & 63, wave = tid >> 6;
    __shared__ float scr[8][4];
    const float a0 = hm[(size_t)ji*DD + tid];
    const float a1 = hm[(size_t)ji*DD + 256 + tid];
    const float a2 = hm[(size_t)ji*DD + 512 + tid];
#define GDOT(k) { const float* Bp = hm + (size_t)(j*8 + k)*DD + tid;             \
        float acc = a0*Bp[0] + a1*Bp[256] + a2*Bp[512];                          \
        acc += __shfl_down(acc, 32); acc += __shfl_down(acc, 16);                \
        acc += __shfl_down(acc, 8);  acc += __shfl_down(acc, 4);                 \
        acc += __shfl_down(acc, 2);  acc += __shfl_down(acc, 1);                 \
        if (lane == 0) scr[k][wave] = acc; }
    FOR8(GDOT)
#undef GDOT
    __syncthreads();
    if (tid < 8) G[ji*8 + tid] = scr[tid][0] + scr[tid][1] + scr[tid][2] + scr[tid][3];
}

// ---------------- kernel 3c: per-n dots dmq[n][ji] = M_ji . q'_nj + q' stats ----
__global__ __launch_bounds__(256) void k_dots(const float* __restrict__ H,
                                              const float* __restrict__ hm,
                                              float* __restrict__ dmq,
                                              float* __restrict__ Sq0v,
                                              float* __restrict__ Sq20v)
{
    const int j = blockIdx.x;           // 0..7
    const int tile = blockIdx.y;        // 0..7 (50 n each)
    const int tid = threadIdx.x;
    const int lane = tid & 63, wave = tid >> 6;   // 4 waves
    __shared__ __align__(16) float Ms[8][768];
    #pragma unroll
    for (int r = 0; r < 8; ++r)
        for (int c = tid; c < DD; c += 256)
            Ms[r][c] = hm[(size_t)(j*8 + r)*DD + c];
    __syncthreads();

    for (int nn = wave; nn < 50; nn += 4) {
        const int n = tile * 50 + nn;
        const float* qp = H + (size_t)n * JD + j * DD;
        float s = 0.f, s2 = 0.f;
#define DCL(k) float d##k = 0.f;
        FOR8(DCL)
#undef DCL
        #pragma unroll 2
        for (int c = 0; c < 12; ++c) {
            const int d = lane + 64 * c;
            const float qv = qp[d];
            s += qv; s2 += qv * qv;
#define MAC(k) d##k += qv * Ms[k][d];
            FOR8(MAC)
#undef MAC
        }
#define XR(v) { v += __shfl_xor(v, 32); v += __shfl_xor(v, 16); v += __shfl_xor(v, 8); \
                v += __shfl_xor(v, 4);  v += __shfl_xor(v, 2);  v += __shfl_xor(v, 1); }
#define XRD(k) XR(d##k)
        FOR8(XRD)
#undef XRD
        XR(s) XR(s2)
#undef XR
        if (lane == 0) {
#define ST(k) dmq[(size_t)n*64 + j*8 + k] = d##k;
            FOR8(ST)
#undef ST
            Sq0v[n*8 + j] = s;
            Sq20v[n*8 + j] = s2;
        }
    }
}

// ---------------- kernel 4: fused routing (3 d-space passes) ----------------
__global__ __launch_bounds__(768) void k_route2(const float* __restrict__ H,
                                                const float* __restrict__ hm,
                                                const float* __restrict__ muM,
                                                const float* __restrict__ mc2M,
                                                const float* __restrict__ G,
                                                const float* __restrict__ dmq,
                                                const float* __restrict__ Sq0v,
                                                const float* __restrict__ Sq20v,
                                                float* __restrict__ out)
{
    const int n = blockIdx.x;
    const int tid = threadIdx.x;                  // d
    const int lane = tid & 63, wave = tid >> 6;   // 12 waves
    __shared__ __align__(16) float sVv[8][768];
    __shared__ float scr[24][12];
    __shared__ float rstat[24];
    __shared__ float sDot[64];
    __shared__ float sP[64], sC1[64], sC2[64], sB1[64];

#define WRED(val, idx) { float _v = (val);                           \
    _v += __shfl_down(_v, 32); _v += __shfl_down(_v, 16);            \
    _v += __shfl_down(_v, 8);  _v += __shfl_down(_v, 4);             \
    _v += __shfl_down(_v, 2);  _v += __shfl_down(_v, 1);             \
    if (lane == 0) scr[(idx)][wave] = _v; }

#define FIN(nv) { if (tid < (nv)) { float _s = 0.f;                  \
    _Pragma("unroll")                                                \
    for (int _w = 0; _w < 12; ++_w) _s += scr[tid][_w];              \
    rstat[tid] = _s; } }

#define DOTLOOP() for (int t = wave; t < 64; t += 12) {              \
        const int _j = t >> 3;                                       \
        const float* Mrow = hm + (size_t)t * DD;                     \
        float acc = 0.f;                                             \
        _Pragma("unroll")                                            \
        for (int c = 0; c < 3; ++c) {                                \
            const int dd = c * 256 + lane * 4;                       \
            const float4 mv = *reinterpret_cast<const float4*>(Mrow + dd);       \
            const float4 vv = *reinterpret_cast<const float4*>(&sVv[_j][dd]);    \
            acc += mv.x*vv.x + mv.y*vv.y + mv.z*vv.z + mv.w*vv.w;    \
        }                                                            \
        acc += __shfl_down(acc, 32); acc += __shfl_down(acc, 16);    \
        acc += __shfl_down(acc, 8);  acc += __shfl_down(acc, 4);     \
        acc += __shfl_down(acc, 2);  acc += __shfl_down(acc, 1);     \
        if (lane == 0) sDot[t] = acc;                                \
    }

#define XR3(v) { v += __shfl_xor(v, 1); v += __shfl_xor(v, 2); v += __shfl_xor(v, 4); }

    // ---- stage 0 (wave 0): coefficient-space routing iteration 1 ----
    float w0 = 0.f, s1 = 0.f, dotM1 = 0.f, Sq1 = 0.f, Sq21 = 0.f, mu = 0.f, mc2 = 0.f;
    if (tid < 64) {
        const int j = lane >> 3;
        mu  = muM[lane];
        mc2 = mc2M[lane];
        const float smR = 768.f * mu;              // sum of M row
        const float dq  = dmq[(size_t)n * 64 + lane];
        const float Sq  = Sq0v[n * 8 + j];
        const float Sq2v = Sq20v[n * 8 + j];
        // p0 -> w0 = 1/8 + p0
        {
            float num  = dq - mu * Sq;
            float varq = fmaxf(Sq2v - Sq * Sq * (1.f / 768.f), 0.f);
            float den  = sqrtf(mc2 * varq) + EPSF;
            w0 = tanhf(num / den) + 0.125f;
        }
        // Gw0
        const float* Gr = G + lane * 8;
        const int base = lane & ~7;
        float gw = 0.f;
        #pragma unroll
        for (int ii = 0; ii < 8; ++ii) gw += Gr[ii] * __shfl(w0, base + ii);
        float n2h1 = w0 * gw;  XR3(n2h1);          // |hv1|^2
        float dqh1 = w0 * dq;  XR3(dqh1);          // dot(q', hv1)
        float Sh1  = w0 * smR; XR3(Sh1);           // sum(hv1)
        s1 = n2h1 / ((1.f + n2h1) * sqrtf(n2h1 + EPSF));
        float c1 = s1 * gw;
        sC1[lane] = c1;
        sB1[lane] = 0.5f * s1 * w0;
        dotM1 = 0.5f * (dq + c1);
        Sq1   = 0.5f * (Sq + s1 * Sh1);
        Sq21  = 0.25f * (Sq2v + 2.f * s1 * dqh1 + s1 * s1 * n2h1);   // |tq1|^2
        float varq1 = fmaxf(Sq21 - Sq1 * Sq1 * (1.f / 768.f), 0.f);
        sP[lane] = tanhf((dotM1 - mu * Sq1) / (sqrtf(mc2 * varq1) + EPSF));  // p1
    }
    __syncthreads();

    // ---- pass 1 (d-space): hv2 + tq1 reconstruction ----
    const float* Hn = H + (size_t)n * JD + tid;
    const float* hmp = hm + tid;
#define DECL(k) float t0_##k = Hn[k * DD]; float tq1_##k = 0.5f * t0_##k; float vh_##k = 0.f;
    FOR8(DECL)
#undef DECL
    #pragma unroll 1
    for (int i = 0; i < 8; ++i) {
#define XA(k) float x##k = t0_##k * sC1[k * 8 + i];
        FOR8(XA)
#undef XA
        float mx = fmaxf(fmaxf(fmaxf(x0, x1), fmaxf(x2, x3)),
                         fmaxf(fmaxf(x4, x5), fmaxf(x6, x7)));
#define XE(k) x##k = expf(x##k - mx);
        FOR8(XE)
#undef XE
        float inv = 1.f / (x0 + x1 + x2 + x3 + x4 + x5 + x6 + x7);
#define XACC(k) { float mval = hmp[(size_t)(k * 8 + i) * DD];        \
        vh_##k  += (x##k * inv + sP[k * 8 + i]) * mval;              \
        tq1_##k += sB1[k * 8 + i] * mval; }
        FOR8(XACC)
#undef XACC
    }
#define STG(k) sVv[k][tid] = vh_##k;                                 \
    WRED(vh_##k * vh_##k, k); WRED(vh_##k, 8 + k); WRED(t0_##k * vh_##k, 16 + k);
    FOR8(STG)
#undef STG
    __syncthreads();
    // ---- pass 2: u[ji] = M_ji . hv2_j ----
    DOTLOOP();
    FIN(24);
    __syncthreads();

    // ---- stage 2 (wave 0): p2, c2 ----
    if (tid < 64) {
        const int j = lane >> 3;
        const float n2h2 = rstat[j];               // |hv2|^2
        const float Sh2  = rstat[8 + j];           // sum(hv2)
        const float dqh2 = rstat[16 + j];          // dot(q', hv2)
        const float u = sDot[lane];                // dot(M_ji, hv2_j)
        float s2 = n2h2 / ((1.f + n2h2) * sqrtf(n2h2 + EPSF));
        float c2 = s2 * u;
        sC2[lane] = c2;
        float dotM2 = 0.5f * (dotM1 + c2);
        float w0u = w0 * u; XR3(w0u);              // dot(hv1, hv2)
        float dt1h2 = 0.5f * (dqh2 + s1 * w0u);    // dot(tq1, hv2)
        float Sq2_ = 0.5f * (Sq1 + s2 * Sh2);
        float Sq22 = 0.25f * Sq21 + 0.5f * s2 * dt1h2 + 0.25f * s2 * s2 * n2h2;  // |tq2|^2
        float varq2 = fmaxf(Sq22 - Sq2_ * Sq2_ * (1.f / 768.f), 0.f);
        sP[lane] = tanhf((dotM2 - mu * Sq2_) / (sqrtf(mc2 * varq2) + EPSF));     // p2
    }
    __syncthreads();

    // ---- pass 3 (d-space): final softmax + hv3 + squash + write ----
#define ZV(k) vh_##k = 0.f;
    FOR8(ZV)
#undef ZV
    #pragma unroll 1
    for (int i = 0; i < 8; ++i) {
#define XA(k) float x##k = t0_##k * sC1[k * 8 + i] + tq1_##k * sC2[k * 8 + i];
        FOR8(XA)
#undef XA
        float mx = fmaxf(fmaxf(fmaxf(x0, x1), fmaxf(x2, x3)),
                         fmaxf(fmaxf(x4, x5), fmaxf(x6, x7)));
#define XE(k) x##k = expf(x##k - mx);
        FOR8(XE)
#undef XE
        float inv = 1.f / (x0 + x1 + x2 + x3 + x4 + x5 + x6 + x7);
#define XACC(k) vh_##k += (x##k * inv + sP[k * 8 + i]) * hmp[(size_t)(k * 8 + i) * DD];
        FOR8(XACC)
#undef XACC
    }
#define NRM(k) WRED(vh_##k * vh_##k, k);
    FOR8(NRM)
#undef NRM
    __syncthreads();
    FIN(8);
    __syncthreads();
    float* On = out + (size_t)n * JD + tid;
#define WOUT(k) { float n2 = rstat[k];                               \
        float sc = n2 / ((1.f + n2) * sqrtf(n2 + EPSF));             \
        On[k * DD] = vh_##k * sc; }
    FOR8(WOUT)
#undef WOUT
#undef WRED
#undef FIN
#undef DOTLOOP
#undef XR3
}

extern "C" void kernel_launch(void* const* d_in, const int* in_sizes, int n_in,
                              void* d_out, int out_size, void* d_ws, size_t ws_size,
                              hipStream_t stream) {
    const float* m  = (const float*)d_in[0];   // [8,768]
    const float* q  = (const float*)d_in[1];   // [400,768]
    const float* W  = (const float*)d_in[2];   // [1,8,8,768,768]
    const float* b  = (const float*)d_in[3];   // [1,8,8,768]
    const float* Wn = (const float*)d_in[4];   // [768,768]
    float* out = (float*)d_out;
    float* ws  = (float*)d_ws;

    float* mproj = ws + OFF_MPROJ;
    float* H     = ws + OFF_H;
    float* hm    = ws + OFF_HM;
    float* muM   = ws + OFF_MU;
    float* mc2M  = ws + OFF_MC2;
    float* G     = ws + OFF_G;
    float* dmq   = ws + OFF_DMQ;
    float* Sq0v  = ws + OFF_SQ0;
    float* Sq20v = ws + OFF_SQ20;
    unsigned short* A2 = (unsigned short*)(ws + OFF_A2);
    unsigned short* B2 = (unsigned short*)(ws + OFF_B2);

    k_mproj<<<dim3(3, 8), 256, 0, stream>>>(m, Wn, mproj);
    k_cvtA<<<dim3(408), 256, 0, stream>>>(q, mproj, A2);
    k_cvtB<<<dim3(6144), 256, 0, stream>>>(W, B2);
    k_gemm_mfma<<<dim3(48, 4), 256, 0, stream>>>(A2, B2, H);
    k_prep<<<dim3(64), 256, 0, stream>>>(H, b, hm, muM, mc2M);
    k_gram<<<dim3(64), 256, 0, stream>>>(hm, G);
    k_dots<<<dim3(8, 8), 256, 0, stream>>>(H, hm, dmq, Sq0v, Sq20v);
    k_route2<<<dim3(400), 768, 0, stream>>>(H, hm, muM, mc2M, G, dmq, Sq0v, Sq20v, out);
}